// Round 13
// baseline (122.371 us; speedup 1.0000x reference)
//
#include <hip/hip_runtime.h>
#include <stdint.h>

#define NT 2048     // tokens
#define TD 1024     // token dim
#define NH 16       // heads
static constexpr float SCL = 0.18033688011112042f;  // beta*log2(e), applied in exp2

typedef __attribute__((ext_vector_type(8))) short bf16x8;
typedef __attribute__((ext_vector_type(4))) float f32x4;
typedef __attribute__((ext_vector_type(16))) float f32x16;
typedef __attribute__((address_space(3))) uint32_t lds_u32;
typedef __attribute__((address_space(1))) uint32_t glb_u32;

__device__ __forceinline__ float bf2f(unsigned short u){
  union { uint32_t u32; float f; } v; v.u32 = ((uint32_t)u) << 16; return v.f;
}
__device__ __forceinline__ unsigned short f2bf(float f){
  union { float f; uint32_t u; } v; v.f = f;
  uint32_t r = v.u + 0x7fffu + ((v.u >> 16) & 1u);   // RNE
  return (unsigned short)(r >> 16);
}
// 128B-row tile (8x16B slots), phys slot = kc ^ (row&7)  (btg2 staging)
__device__ __forceinline__ bf16x8 ld8(const unsigned short* base, int row, int kc){
  return *(const bf16x8*)((const char*)base + row*128 + ((kc ^ (row & 7)) << 4));
}
template<int N> __device__ __forceinline__ void wait_vm_lgkm0(){
  if constexpr (N == 0)      asm volatile("s_waitcnt vmcnt(0) lgkmcnt(0)" ::: "memory");
  else if constexpr (N == 4) asm volatile("s_waitcnt vmcnt(4) lgkmcnt(0)" ::: "memory");
  else if constexpr (N == 6) asm volatile("s_waitcnt vmcnt(6) lgkmcnt(0)" ::: "memory");
  __builtin_amdgcn_sched_barrier(0);
}

// ------------------------------------------------------------------
// prep: gbf = bf16(g); wkq = bf16([Wk;Wq]) rows hz2 x 1024;
//       twqk[d][j] = j<1024 ? Wq[j][d] : Wk[j-1024][d]  (bf16, 1024x2048)
// ------------------------------------------------------------------
__global__ __launch_bounds__(256) void prep_kernel(
    const float* __restrict__ g, const float* __restrict__ Wk, const float* __restrict__ Wq,
    unsigned short* __restrict__ gbf, unsigned short* __restrict__ wkq,
    unsigned short* __restrict__ twqk)
{
  int b = blockIdx.x;
  if (b < 1024) {
    int base = b * 2048 + threadIdx.x;
    #pragma unroll
    for (int i = 0; i < 8; i++) { int idx = base + i * 256; gbf[idx] = f2bf(g[idx]); }
  } else if (b < 2048) {
    int base = (b - 1024) * 2048 + threadIdx.x;
    #pragma unroll
    for (int i = 0; i < 8; i++) {
      int idx = base + i * 256;
      float v = (idx < (1 << 20)) ? Wk[idx] : Wq[idx - (1 << 20)];
      wkq[idx] = f2bf(v);
    }
  } else {
    int t = b - 2048;                  // 32 d-tiles x 64 j-tiles
    int dt = t & 31, jt = t >> 5;
    __shared__ float tile[32][33];
    int tx = threadIdx.x & 31, ty = threadIdx.x >> 5;
    int j0 = jt * 32, d0 = dt * 32;
    const float* src = (j0 < 1024) ? Wq : Wk;
    int jb = (j0 < 1024) ? j0 : (j0 - 1024);
    #pragma unroll
    for (int rr = 0; rr < 4; rr++)
      tile[ty + rr * 8][tx] = src[(size_t)(jb + ty + rr * 8) * 1024 + d0 + tx];
    __syncthreads();
    #pragma unroll
    for (int rr = 0; rr < 4; rr++)
      twqk[(size_t)(d0 + ty + rr * 8) * 2048 + j0 + tx] = f2bf(tile[tx][ty + rr * 8]);
  }
}

// ------------------------------------------------------------------
// pack_pck: PCK fragment layout for S-operands (A and B share the map).
//   fragment (cb in [0,32), rb in [0,64), kz in [0,4)): lane l, elem e:
//     tok = rb*32 + (l&31);  z = kz*16 + 8*(l>>5) + e;  col = cb*64 + z
//   flat bf16x8 index: ((cb*64+rb)*4 + kz)*64 + l
// ------------------------------------------------------------------
__global__ __launch_bounds__(256) void pack_pck(const unsigned short* __restrict__ CKQ,
                                                unsigned short* __restrict__ PCK)
{
  int tile = blockIdx.x;             // 2048 = 32 cb x 64 rb
  int cb = tile >> 6, rb = tile & 63;
  __shared__ unsigned short t[32][72];   // 32 tok x 64 z (stride 144B, 8B-aligned)
  int tid = threadIdx.x;
  int r = tid >> 3, c0 = (tid & 7) * 8;
  const unsigned short* src = CKQ + (size_t)(rb * 32 + r) * 2048 + cb * 64 + c0;
  *(ushort4*)&t[r][c0]     = *(const ushort4*)src;
  *(ushort4*)&t[r][c0 + 4] = *(const ushort4*)(src + 4);
  __syncthreads();
  int kz = tid >> 6, l = tid & 63;
  int zl = kz * 16 + 8 * (l >> 5);
  ushort4 lo = *(ushort4*)&t[l & 31][zl];
  ushort4 hi4 = *(ushort4*)&t[l & 31][zl + 4];
  unsigned short* dst = PCK + ((size_t)(tile * 4 + kz) * 64 + l) * 8;
  *(ushort4*)dst       = lo;
  *(ushort4*)(dst + 4) = hi4;
}

// ------------------------------------------------------------------
// pack_pbx: PBT (DIVL=false: K^T) / QSTP (DIVL=true: Q^T / L) PV-B fragments.
//   fragment ((h,zb), qb in [0,64), ks in [0,2)): lane l, elem e:
//     z-row = h*64 + zb*32 + (l&31)
//     q     = qb*32 + 16*ks + 8*(e>>2) + 4*(l>>5) + (e&3)     [sigma baked in]
//     value = CKQ[q][colbase + (l&31)]  (/ L[h][q] for QSTP)
// ------------------------------------------------------------------
template<bool DIVL>
__global__ __launch_bounds__(256) void pack_pbx(const unsigned short* __restrict__ CKQ,
                                                const float* __restrict__ L,
                                                unsigned short* __restrict__ PBX)
{
  int bid = blockIdx.x;              // 2048 = (16h x 2zb) x 64 qb
  int qb = bid & 63, hz = bid >> 6;  // hz = h*2+zb
  int h = hz >> 1, zb = hz & 1;
  int colbase = (DIVL ? 1024 : 0) + h * 64 + zb * 32;
  __shared__ unsigned short tq[32][36];   // [q-local][z-local]
  __shared__ float rcpL[32];
  int tid = threadIdx.x;
  int r = tid >> 3, c0 = (tid & 7) * 4;
  *(ushort4*)&tq[r][c0] =
      *(const ushort4*)(CKQ + (size_t)(qb * 32 + r) * 2048 + colbase + c0);
  if (DIVL && tid < 32) rcpL[tid] = 1.0f / L[(size_t)h * NT + qb * 32 + tid];
  __syncthreads();
  if (tid < 128) {
    int ks = tid >> 6, l = tid & 63;
    int zl = l & 31, hi = l >> 5;
    unsigned short ob[8];
    #pragma unroll
    for (int e = 0; e < 8; e++) {
      int ql = 16 * ks + 8 * (e >> 2) + 4 * hi + (e & 3);
      unsigned short v = tq[ql][zl];
      if (DIVL) v = f2bf(bf2f(v) * rcpL[ql]);
      ob[e] = v;
    }
    unsigned short* dst = PBX + ((size_t)(bid * 2 + ks) * 64 + l) * 8;
    *(ushort4*)dst       = *(ushort4*)&ob[0];
    *(ushort4*)(dst + 4) = *(ushort4*)&ob[4];
  }
}

// ------------------------------------------------------------------
// btg2: C = A[M x K] * BT[N x K]^T, bf16, BK=64, triple-buffered counted vmcnt.
// blockIdx.z = K-split index (kb = z*Kdim).
// EPI 0: C0 = bf16 C (ld 2048)                                       [KQ]
// EPI 5: C0 f32 partial [z][r][1024] = acc (no negate)               [out]
// ------------------------------------------------------------------
template<int TM, int TN, int EPI, int WPE>
__global__ __launch_bounds__(256, WPE) void btg2_kernel(
    const unsigned short* __restrict__ A, int lda,
    const unsigned short* __restrict__ BT, int ldb,
    int Kdim, void* C0)
{
  constexpr int WM = TM / 2, WN = TN / 2, FM = WM / 16, FN = WN / 16;
  constexpr int AC = TM / 32, BC = TN / 32, LOADS = AC + BC;
  __shared__ __align__(16) unsigned short As[3][TM * 64];
  __shared__ __align__(16) unsigned short Bs[3][TN * 64];
  int tid = threadIdx.x, lane = tid & 63, wave = tid >> 6;
  int wr = wave >> 1, wc = wave & 1, lrow = lane & 15, g = lane >> 4;
  int bm = blockIdx.x * TM, bn = blockIdx.y * TN;
  int kb = blockIdx.z * Kdim;

  auto stage = [&](unsigned short* bufA, unsigned short* bufB, int kk) {
    #pragma unroll
    for (int i = 0; i < AC; i++) {
      int c = i * 256 + tid, row = c >> 3, sl = ((c & 7) ^ (row & 7)) << 3;
      __builtin_amdgcn_global_load_lds((glb_u32*)(A + (size_t)(bm + row) * lda + kb + kk + sl),
          (lds_u32*)((char*)bufA + i * 4096 + wave * 1024), 16, 0, 0);
    }
    #pragma unroll
    for (int i = 0; i < BC; i++) {
      int c = i * 256 + tid, row = c >> 3, sl = ((c & 7) ^ (row & 7)) << 3;
      __builtin_amdgcn_global_load_lds((glb_u32*)(BT + (size_t)(bn + row) * ldb + kb + kk + sl),
          (lds_u32*)((char*)bufB + i * 4096 + wave * 1024), 16, 0, 0);
    }
  };

  f32x4 acc[FM][FN] = {};
  int nt = Kdim >> 6;
  stage(As[0], Bs[0], 0);
  stage(As[1], Bs[1], 64);
  wait_vm_lgkm0<LOADS>();          // tile0 landed; tile1 still in flight
  __builtin_amdgcn_s_barrier();
  int bc = 0;
  for (int t = 0; t < nt; t++) {
    int bp = bc + 2; if (bp >= 3) bp -= 3;
    if (t + 2 < nt) stage(As[bp], Bs[bp], (t + 2) * 64);
    const unsigned short* Ac = As[bc];
    const unsigned short* Bc = Bs[bc];
    #pragma unroll
    for (int k2 = 0; k2 < 2; k2++) {
      bf16x8 a_[FM], b_[FN];
      #pragma unroll
      for (int m = 0; m < FM; m++) a_[m] = ld8(Ac, wr * WM + m * 16 + lrow, k2 * 4 + g);
      #pragma unroll
      for (int n = 0; n < FN; n++) b_[n] = ld8(Bc, wc * WN + n * 16 + lrow, k2 * 4 + g);
      #pragma unroll
      for (int m = 0; m < FM; m++)
        #pragma unroll
        for (int n = 0; n < FN; n++)
          acc[m][n] = __builtin_amdgcn_mfma_f32_16x16x32_bf16(a_[m], b_[n], acc[m][n], 0, 0, 0);
    }
    if (t + 2 < nt) wait_vm_lgkm0<LOADS>(); else wait_vm_lgkm0<0>();
    __builtin_amdgcn_s_barrier();
    bc = (bc == 2) ? 0 : bc + 1;
  }
  #pragma unroll
  for (int m = 0; m < FM; m++) {
    int rb = bm + wr * WM + m * 16 + 4 * g;
    #pragma unroll
    for (int n = 0; n < FN; n++) {
      int cc = bn + wc * WN + n * 16 + lrow;
      f32x4 v = acc[m][n];
      if constexpr (EPI == 0) {
        unsigned short* Cp = (unsigned short*)C0;
        #pragma unroll
        for (int j = 0; j < 4; j++) Cp[(size_t)(rb + j) * 2048 + cc] = f2bf(v[j]);
      } else {
        float* Cf = (float*)C0 + (size_t)blockIdx.z * ((size_t)NT * 1024);
        #pragma unroll
        for (int j = 0; j < 4; j++) Cf[(size_t)(rb + j) * 1024 + cc] = v[j];
      }
    }
  }
}

// ------------------------------------------------------------------
// comb: d_out = -(P0 + P1)   (f32, 2M elems)
// ------------------------------------------------------------------
__global__ __launch_bounds__(256) void comb_kernel(const float* __restrict__ P,
                                                   float* __restrict__ out)
{
  int i = (blockIdx.x * 256 + threadIdx.x) * 4;
  f32x4 a = *(const f32x4*)&P[i];
  f32x4 b = *(const f32x4*)&P[i + ((size_t)NT * 1024)];
  f32x4 r;
  #pragma unroll
  for (int j = 0; j < 4; j++) r[j] = -(a[j] + b[j]);
  *(f32x4*)&out[i] = r;
}

// ------------------------------------------------------------------
// fused v13: zero-barrier packed-load kernel (v12-verified fragments) with
// T15 double-pipeline: PV lags S by one iteration, so PV(t-1) overlaps the
// loads and S/exp of iteration t (independent register chains).
// ------------------------------------------------------------------
template<bool DIV>
__global__ __launch_bounds__(256, 2) void fused_kernel(
    const unsigned short* __restrict__ PCK,   // packed CKQ fragments
    const unsigned short* __restrict__ PBX,   // PBT (F1) or QSTP (F2)
    unsigned short* __restrict__ C,           // CB12 [2048][2048]
    float* __restrict__ Lg)                   // [16][2048] (F1 only)
{
  __shared__ __align__(16) float Red[2][64][68];   // ~34.8 KB
  __shared__ float L_lds[64];
  int tid = threadIdx.x, l = tid & 63, w = tid >> 6;
  int zr = l & 31, hi = l >> 5;
  int lin = blockIdx.x;                      // 512 blocks, bijective XCD swizzle
  int wgid = (lin & 7) * 64 + (lin >> 3);
  int h = wgid >> 5, pB = wgid & 31, p0 = pB * 64;
  int cbA = DIV ? h : 16 + h;                // inner cols (F1: K, F2: Q)
  int cbB = DIV ? 16 + h : h;                // persist cols (F1: Q, F2: K)
  const bf16x8* PCKf = (const bf16x8*)PCK;
  const bf16x8* PBXf = (const bf16x8*)PBX;

  // persistent S B-fragments (2 x 32-persist sets)
  bf16x8 bs[2][4];
  #pragma unroll
  for (int ps = 0; ps < 2; ps++)
    #pragma unroll
    for (int kz = 0; kz < 4; kz++)
      bs[ps][kz] = PCKf[((size_t)(cbB * 64 + pB * 2 + ps) * 4 + kz) * 64 + l];

  auto loadA = [&](bf16x8 (&a_)[4], int rb){
    #pragma unroll
    for (int kz = 0; kz < 4; kz++)
      a_[kz] = PCKf[((size_t)(cbA * 64 + rb) * 4 + kz) * 64 + l];
  };
  auto loadB = [&](bf16x8 (&pb_)[2][2], int rb){
    #pragma unroll
    for (int zb = 0; zb < 2; zb++)
      #pragma unroll
      for (int ks = 0; ks < 2; ks++)
        pb_[zb][ks] = PBXf[((size_t)((h * 2 + zb) * 64 + rb) * 2 + ks) * 64 + l];
  };

  union upk { bf16x8 v; uint32_t u[4]; };
  auto do_S = [&](upk (&pu)[2][2], const bf16x8 (&a_)[4], float (&ls)[2]){
    f32x16 acc_s[2] = {};
    #pragma unroll
    for (int kz = 0; kz < 4; kz++) {
      acc_s[0] = __builtin_amdgcn_mfma_f32_32x32x16_bf16(a_[kz], bs[0][kz], acc_s[0], 0, 0, 0);
      acc_s[1] = __builtin_amdgcn_mfma_f32_32x32x16_bf16(a_[kz], bs[1][kz], acc_s[1], 0, 0, 0);
    }
    #pragma unroll
    for (int ps = 0; ps < 2; ps++) {
      float ev[16];
      #pragma unroll
      for (int r = 0; r < 16; r++) ev[r] = exp2f(acc_s[ps][r] * SCL);
      if (DIV) {
        #pragma unroll
        for (int r = 0; r < 16; r++) ls[ps] += ev[r];
      }
      #pragma unroll
      for (int ks = 0; ks < 2; ks++)
        #pragma unroll
        for (int i = 0; i < 4; i++)
          asm("v_cvt_pk_bf16_f32 %0, %1, %2"
              : "=v"(pu[ps][ks].u[i]) : "v"(ev[8 * ks + 2 * i]), "v"(ev[8 * ks + 2 * i + 1]));
    }
  };

  f32x16 acc_pv[2][2] = {};                  // [ps][zb]
  float lsum[2] = {0.f, 0.f};
  bf16x8 a_[4], pb_[2][2];
  upk pu[2][2];

  // iteration 0: load + S + exp (no PV yet)
  loadA(a_, w * 16);
  loadB(pb_, w * 16);
  do_S(pu, a_, lsum);

  for (int t = 1; t < 16; t++) {
    bf16x8 an[4]; bf16x8 pbn[2][2];
    loadA(an, w * 16 + t);
    loadB(pbn, w * 16 + t);
    // PV(t-1): independent of this iteration's loads and exp
    #pragma unroll
    for (int zb = 0; zb < 2; zb++)
      #pragma unroll
      for (int ks = 0; ks < 2; ks++) {
        acc_pv[0][zb] = __builtin_amdgcn_mfma_f32_32x32x16_bf16(pu[0][ks].v, pb_[zb][ks], acc_pv[0][zb], 0, 0, 0);
        acc_pv[1][zb] = __builtin_amdgcn_mfma_f32_32x32x16_bf16(pu[1][ks].v, pb_[zb][ks], acc_pv[1][zb], 0, 0, 0);
      }
    // S(t) + exp(t) -> pu (overwrites; PV(t-1) already consumed old pu)
    do_S(pu, an, lsum);
    #pragma unroll
    for (int zb = 0; zb < 2; zb++)
      #pragma unroll
      for (int ks = 0; ks < 2; ks++) pb_[zb][ks] = pbn[zb][ks];
  }
  // final PV(15)
  #pragma unroll
  for (int zb = 0; zb < 2; zb++)
    #pragma unroll
    for (int ks = 0; ks < 2; ks++) {
      acc_pv[0][zb] = __builtin_amdgcn_mfma_f32_32x32x16_bf16(pu[0][ks].v, pb_[zb][ks], acc_pv[0][zb], 0, 0, 0);
      acc_pv[1][zb] = __builtin_amdgcn_mfma_f32_32x32x16_bf16(pu[1][ks].v, pb_[zb][ks], acc_pv[1][zb], 0, 0, 0);
    }

  // ---- cross-wave (4 inner-quarter) two-phase reduction (v12-verified)
  if (w >= 2) {
    #pragma unroll
    for (int ps = 0; ps < 2; ps++)
      #pragma unroll
      for (int zb = 0; zb < 2; zb++) {
        int z = zb * 32 + zr;
        #pragma unroll
        for (int u = 0; u < 4; u++) {
          int p = ps * 32 + 8 * u + 4 * hi;
          f32x4 q;
          q[0] = acc_pv[ps][zb][4 * u];     q[1] = acc_pv[ps][zb][4 * u + 1];
          q[2] = acc_pv[ps][zb][4 * u + 2]; q[3] = acc_pv[ps][zb][4 * u + 3];
          *(f32x4*)&Red[w - 2][z][p] = q;
        }
      }
  }
  if (DIV && tid < 64) L_lds[tid] = 0.f;
  __syncthreads();
  if (w < 2) {
    #pragma unroll
    for (int ps = 0; ps < 2; ps++)
      #pragma unroll
      for (int zb = 0; zb < 2; zb++) {
        int z = zb * 32 + zr;
        #pragma unroll
        for (int u = 0; u < 4; u++) {
          int p = ps * 32 + 8 * u + 4 * hi;
          float* slot = &Red[w][z][p];
          f32x4 q = *(f32x4*)slot;
          q[0] += acc_pv[ps][zb][4 * u];     q[1] += acc_pv[ps][zb][4 * u + 1];
          q[2] += acc_pv[ps][zb][4 * u + 2]; q[3] += acc_pv[ps][zb][4 * u + 3];
          *(f32x4*)slot = q;
        }
      }
  }
  if (DIV) {
    #pragma unroll
    for (int ps = 0; ps < 2; ps++) {
      float s = lsum[ps];
      s += __shfl_xor(s, 32);                // combine hi halves (same persist col)
      if (hi == 0) atomicAdd(&L_lds[ps * 32 + zr], s);
    }
  }
  __syncthreads();
  if (DIV && tid < 64) Lg[(size_t)h * NT + p0 + tid] = L_lds[tid];
  // output: thread -> p = tid>>2 (0..63), z-range (tid&3)*16
  int p = tid >> 2, z16 = (tid & 3) * 16;
  float inv = DIV ? 1.0f / L_lds[p] : 1.0f;
  int cbase = DIV ? h * 64 : TD + h * 64;
  unsigned short ob[16];
  #pragma unroll
  for (int i = 0; i < 16; i++) {
    int z = z16 + i;
    float x = Red[0][z][p] + Red[1][z][p];
    ob[i] = f2bf(x * inv);
  }
  unsigned short* dst = C + (size_t)(p0 + p) * 2048 + cbase + z16;
  *(ushort4*)dst        = *(ushort4*)&ob[0];
  *(ushort4*)(dst + 4)  = *(ushort4*)&ob[4];
  *(ushort4*)(dst + 8)  = *(ushort4*)&ob[8];
  *(ushort4*)(dst + 12) = *(ushort4*)&ob[12];
}

// ------------------------------------------------------------------
extern "C" void kernel_launch(void* const* d_in, const int* in_sizes, int n_in,
                              void* d_out, int out_size, void* d_ws, size_t ws_size,
                              hipStream_t stream)
{
  (void)in_sizes; (void)n_in; (void)out_size; (void)ws_size;
  const float* g  = (const float*)d_in[0];
  const float* Wk = (const float*)d_in[1];
  const float* Wq = (const float*)d_in[2];

  char* ws = (char*)d_ws;
  size_t off = 0;
  auto alloc = [&](size_t b) -> char* {
    char* p = ws + off; off += (b + 255) & ~((size_t)255); return p;
  };
  unsigned short* gbf  = (unsigned short*)alloc((size_t)NT * TD * 2);     // 4 MB
  unsigned short* wkq  = (unsigned short*)alloc((size_t)2 * TD * TD * 2); // 4 MB
  unsigned short* twqk = (unsigned short*)alloc((size_t)TD * 2048 * 2);   // 4 MB
  unsigned short* CKQ  = (unsigned short*)alloc((size_t)NT * 2048 * 2);   // 8 MB
  unsigned short* PCK  = (unsigned short*)alloc((size_t)NT * 2048 * 2);   // 8 MB
  unsigned short* PBT  = (unsigned short*)alloc((size_t)TD * NT * 2);     // 4 MB
  unsigned short* QSTP = (unsigned short*)alloc((size_t)TD * NT * 2);     // 4 MB
  unsigned short* CB12 = (unsigned short*)alloc((size_t)NT * 2048 * 2);   // 8 MB
  float*          PART = (float*)alloc((size_t)2 * NT * 1024 * 4);        // 16 MB
  float*          Lbuf = (float*)alloc((size_t)NH * NT * 4);              // 128 KB

  prep_kernel<<<dim3(4096), dim3(256), 0, stream>>>(g, Wk, Wq, gbf, wkq, twqk);

  // K,Q = g * [Wk;Wq]^T -> CKQ [tok][2048] (row-major)
  btg2_kernel<128, 64, 0, 2><<<dim3(16, 32, 1), dim3(256), 0, stream>>>(
      gbf, TD, wkq, TD, TD, (void*)CKQ);

  // packed operand layouts
  pack_pck<<<dim3(2048), dim3(256), 0, stream>>>(CKQ, PCK);
  pack_pbx<false><<<dim3(2048), dim3(256), 0, stream>>>(CKQ, nullptr, PBT);

  // F1: B1 (normalized) -> CB12 cols [h*64, h*64+64), plus L
  fused_kernel<true><<<dim3(512), dim3(256), 0, stream>>>(PCK, PBT, CB12, Lbuf);

  // QSTP = packed Q^T / L
  pack_pbx<true><<<dim3(2048), dim3(256), 0, stream>>>(CKQ, Lbuf, QSTP);

  // F2: B2 -> CB12 cols [1024+h*64, ...)
  fused_kernel<false><<<dim3(512), dim3(256), 0, stream>>>(PCK, QSTP, CB12, nullptr);

  // out partials: PART[z] = CB12 * twqk^T over K-half z   (f32)
  btg2_kernel<64, 64, 5, 3><<<dim3(32, 16, 2), dim3(256), 0, stream>>>(
      CB12, 2048, twqk, 2048, 1024, (void*)PART);

  // d_out = -(P0 + P1)
  comb_kernel<<<dim3(2048), dim3(256), 0, stream>>>(PART, (float*)d_out);
}

// Round 14
// 117.613 us; speedup vs baseline: 1.0405x; 1.0405x over previous
//
#include <hip/hip_runtime.h>
#include <stdint.h>

#define NT 2048     // tokens
#define TD 1024     // token dim
#define NH 16       // heads
static constexpr float SCL = 0.18033688011112042f;  // beta*log2(e), applied in exp2

typedef __attribute__((ext_vector_type(8))) short bf16x8;
typedef __attribute__((ext_vector_type(4))) float f32x4;
typedef __attribute__((ext_vector_type(16))) float f32x16;
typedef __attribute__((address_space(3))) uint32_t lds_u32;
typedef __attribute__((address_space(1))) uint32_t glb_u32;

__device__ __forceinline__ float bf2f(unsigned short u){
  union { uint32_t u32; float f; } v; v.u32 = ((uint32_t)u) << 16; return v.f;
}
__device__ __forceinline__ unsigned short f2bf(float f){
  union { float f; uint32_t u; } v; v.f = f;
  uint32_t r = v.u + 0x7fffu + ((v.u >> 16) & 1u);   // RNE
  return (unsigned short)(r >> 16);
}
// 128B-row tile (8x16B slots), phys slot = kc ^ (row&7)  (btg2 staging)
__device__ __forceinline__ bf16x8 ld8(const unsigned short* base, int row, int kc){
  return *(const bf16x8*)((const char*)base + row*128 + ((kc ^ (row & 7)) << 4));
}
template<int N> __device__ __forceinline__ void wait_vm_lgkm0(){
  if constexpr (N == 0)      asm volatile("s_waitcnt vmcnt(0) lgkmcnt(0)" ::: "memory");
  else if constexpr (N == 4) asm volatile("s_waitcnt vmcnt(4) lgkmcnt(0)" ::: "memory");
  else if constexpr (N == 6) asm volatile("s_waitcnt vmcnt(6) lgkmcnt(0)" ::: "memory");
  __builtin_amdgcn_sched_barrier(0);
}

// ------------------------------------------------------------------
// prep: gbf = bf16(g); wkq = bf16([Wk;Wq]) rows hz2 x 1024;
//       twqk[d][j] = j<1024 ? Wq[j][d] : Wk[j-1024][d]  (bf16, 1024x2048)
// ------------------------------------------------------------------
__global__ __launch_bounds__(256) void prep_kernel(
    const float* __restrict__ g, const float* __restrict__ Wk, const float* __restrict__ Wq,
    unsigned short* __restrict__ gbf, unsigned short* __restrict__ wkq,
    unsigned short* __restrict__ twqk)
{
  int b = blockIdx.x;
  if (b < 1024) {
    int base = b * 2048 + threadIdx.x;
    #pragma unroll
    for (int i = 0; i < 8; i++) { int idx = base + i * 256; gbf[idx] = f2bf(g[idx]); }
  } else if (b < 2048) {
    int base = (b - 1024) * 2048 + threadIdx.x;
    #pragma unroll
    for (int i = 0; i < 8; i++) {
      int idx = base + i * 256;
      float v = (idx < (1 << 20)) ? Wk[idx] : Wq[idx - (1 << 20)];
      wkq[idx] = f2bf(v);
    }
  } else {
    int t = b - 2048;                  // 32 d-tiles x 64 j-tiles
    int dt = t & 31, jt = t >> 5;
    __shared__ float tile[32][33];
    int tx = threadIdx.x & 31, ty = threadIdx.x >> 5;
    int j0 = jt * 32, d0 = dt * 32;
    const float* src = (j0 < 1024) ? Wq : Wk;
    int jb = (j0 < 1024) ? j0 : (j0 - 1024);
    #pragma unroll
    for (int rr = 0; rr < 4; rr++)
      tile[ty + rr * 8][tx] = src[(size_t)(jb + ty + rr * 8) * 1024 + d0 + tx];
    __syncthreads();
    #pragma unroll
    for (int rr = 0; rr < 4; rr++)
      twqk[(size_t)(d0 + ty + rr * 8) * 2048 + j0 + tx] = f2bf(tile[tx][ty + rr * 8]);
  }
}

// ------------------------------------------------------------------
// pack_pck: PCK fragment layout for S-operands (A and B share the map).
//   fragment (cb in [0,32), rb in [0,64), kz in [0,4)): lane l, elem e:
//     tok = rb*32 + (l&31);  z = kz*16 + 8*(l>>5) + e;  col = cb*64 + z
//   flat bf16x8 index: ((cb*64+rb)*4 + kz)*64 + l
// ------------------------------------------------------------------
__global__ __launch_bounds__(256) void pack_pck(const unsigned short* __restrict__ CKQ,
                                                unsigned short* __restrict__ PCK)
{
  int tile = blockIdx.x;             // 2048 = 32 cb x 64 rb
  int cb = tile >> 6, rb = tile & 63;
  __shared__ unsigned short t[32][72];   // 32 tok x 64 z (stride 144B, 8B-aligned)
  int tid = threadIdx.x;
  int r = tid >> 3, c0 = (tid & 7) * 8;
  const unsigned short* src = CKQ + (size_t)(rb * 32 + r) * 2048 + cb * 64 + c0;
  *(ushort4*)&t[r][c0]     = *(const ushort4*)src;
  *(ushort4*)&t[r][c0 + 4] = *(const ushort4*)(src + 4);
  __syncthreads();
  int kz = tid >> 6, l = tid & 63;
  int zl = kz * 16 + 8 * (l >> 5);
  ushort4 lo = *(ushort4*)&t[l & 31][zl];
  ushort4 hi4 = *(ushort4*)&t[l & 31][zl + 4];
  unsigned short* dst = PCK + ((size_t)(tile * 4 + kz) * 64 + l) * 8;
  *(ushort4*)dst       = lo;
  *(ushort4*)(dst + 4) = hi4;
}

// ------------------------------------------------------------------
// pack_pbx: PBT (DIVL=false: K^T) / QSTP (DIVL=true: Q^T / L) PV-B fragments.
//   fragment ((h,zb), qb in [0,64), ks in [0,2)): lane l, elem e:
//     z-row = h*64 + zb*32 + (l&31)
//     q     = qb*32 + 16*ks + 8*(e>>2) + 4*(l>>5) + (e&3)     [sigma baked in]
//     value = CKQ[q][colbase + (l&31)]  (/ L[h][q] for QSTP)
// ------------------------------------------------------------------
template<bool DIVL>
__global__ __launch_bounds__(256) void pack_pbx(const unsigned short* __restrict__ CKQ,
                                                const float* __restrict__ L,
                                                unsigned short* __restrict__ PBX)
{
  int bid = blockIdx.x;              // 2048 = (16h x 2zb) x 64 qb
  int qb = bid & 63, hz = bid >> 6;  // hz = h*2+zb
  int h = hz >> 1, zb = hz & 1;
  int colbase = (DIVL ? 1024 : 0) + h * 64 + zb * 32;
  __shared__ unsigned short tq[32][36];   // [q-local][z-local]
  __shared__ float rcpL[32];
  int tid = threadIdx.x;
  int r = tid >> 3, c0 = (tid & 7) * 4;
  *(ushort4*)&tq[r][c0] =
      *(const ushort4*)(CKQ + (size_t)(qb * 32 + r) * 2048 + colbase + c0);
  if (DIVL && tid < 32) rcpL[tid] = 1.0f / L[(size_t)h * NT + qb * 32 + tid];
  __syncthreads();
  if (tid < 128) {
    int ks = tid >> 6, l = tid & 63;
    int zl = l & 31, hi = l >> 5;
    unsigned short ob[8];
    #pragma unroll
    for (int e = 0; e < 8; e++) {
      int ql = 16 * ks + 8 * (e >> 2) + 4 * hi + (e & 3);
      unsigned short v = tq[ql][zl];
      if (DIVL) v = f2bf(bf2f(v) * rcpL[ql]);
      ob[e] = v;
    }
    unsigned short* dst = PBX + ((size_t)(bid * 2 + ks) * 64 + l) * 8;
    *(ushort4*)dst       = *(ushort4*)&ob[0];
    *(ushort4*)(dst + 4) = *(ushort4*)&ob[4];
  }
}

// ------------------------------------------------------------------
// btg2: C = A[M x K] * BT[N x K]^T, bf16, BK=64, triple-buffered counted vmcnt.
// EPI 0: C0 = bf16 C (ld 2048), coalesced rows only                  [KQ]
// EPI 4: C0 f32 [r][1024] = -acc                                     [out]
// ------------------------------------------------------------------
template<int TM, int TN, int EPI, int WPE>
__global__ __launch_bounds__(256, WPE) void btg2_kernel(
    const unsigned short* __restrict__ A, int lda,
    const unsigned short* __restrict__ BT, int ldb,
    int Kdim, void* C0)
{
  constexpr int WM = TM / 2, WN = TN / 2, FM = WM / 16, FN = WN / 16;
  constexpr int AC = TM / 32, BC = TN / 32, LOADS = AC + BC;
  __shared__ __align__(16) unsigned short As[3][TM * 64];
  __shared__ __align__(16) unsigned short Bs[3][TN * 64];
  int tid = threadIdx.x, lane = tid & 63, wave = tid >> 6;
  int wr = wave >> 1, wc = wave & 1, lrow = lane & 15, g = lane >> 4;
  int bm = blockIdx.x * TM, bn = blockIdx.y * TN;

  auto stage = [&](unsigned short* bufA, unsigned short* bufB, int kk) {
    #pragma unroll
    for (int i = 0; i < AC; i++) {
      int c = i * 256 + tid, row = c >> 3, sl = ((c & 7) ^ (row & 7)) << 3;
      __builtin_amdgcn_global_load_lds((glb_u32*)(A + (size_t)(bm + row) * lda + kk + sl),
          (lds_u32*)((char*)bufA + i * 4096 + wave * 1024), 16, 0, 0);
    }
    #pragma unroll
    for (int i = 0; i < BC; i++) {
      int c = i * 256 + tid, row = c >> 3, sl = ((c & 7) ^ (row & 7)) << 3;
      __builtin_amdgcn_global_load_lds((glb_u32*)(BT + (size_t)(bn + row) * ldb + kk + sl),
          (lds_u32*)((char*)bufB + i * 4096 + wave * 1024), 16, 0, 0);
    }
  };

  f32x4 acc[FM][FN] = {};
  int nt = Kdim >> 6;
  stage(As[0], Bs[0], 0);
  stage(As[1], Bs[1], 64);
  wait_vm_lgkm0<LOADS>();          // tile0 landed; tile1 still in flight
  __builtin_amdgcn_s_barrier();
  int bc = 0;
  for (int t = 0; t < nt; t++) {
    int bp = bc + 2; if (bp >= 3) bp -= 3;
    if (t + 2 < nt) stage(As[bp], Bs[bp], (t + 2) * 64);
    const unsigned short* Ac = As[bc];
    const unsigned short* Bc = Bs[bc];
    #pragma unroll
    for (int k2 = 0; k2 < 2; k2++) {
      bf16x8 a_[FM], b_[FN];
      #pragma unroll
      for (int m = 0; m < FM; m++) a_[m] = ld8(Ac, wr * WM + m * 16 + lrow, k2 * 4 + g);
      #pragma unroll
      for (int n = 0; n < FN; n++) b_[n] = ld8(Bc, wc * WN + n * 16 + lrow, k2 * 4 + g);
      #pragma unroll
      for (int m = 0; m < FM; m++)
        #pragma unroll
        for (int n = 0; n < FN; n++)
          acc[m][n] = __builtin_amdgcn_mfma_f32_16x16x32_bf16(a_[m], b_[n], acc[m][n], 0, 0, 0);
    }
    if (t + 2 < nt) wait_vm_lgkm0<LOADS>(); else wait_vm_lgkm0<0>();
    __builtin_amdgcn_s_barrier();
    bc = (bc == 2) ? 0 : bc + 1;
  }
  #pragma unroll
  for (int m = 0; m < FM; m++) {
    int rb = bm + wr * WM + m * 16 + 4 * g;
    #pragma unroll
    for (int n = 0; n < FN; n++) {
      int cc = bn + wc * WN + n * 16 + lrow;
      f32x4 v = acc[m][n];
      if constexpr (EPI == 0) {
        unsigned short* Cp = (unsigned short*)C0;
        #pragma unroll
        for (int j = 0; j < 4; j++) Cp[(size_t)(rb + j) * 2048 + cc] = f2bf(v[j]);
      } else {
        float* Cf = (float*)C0;
        #pragma unroll
        for (int j = 0; j < 4; j++) Cf[(size_t)(rb + j) * 1024 + cc] = -v[j];
      }
    }
  }
}

// ------------------------------------------------------------------
// fused v12 (verified, 111.8 us config): zero-barrier, zero-LDS main loop
// with COALESCED packed loads. Each wave autonomous: (head, persist-64,
// inner-512); per iter: 4 a-loads + 4 pb-loads (global_load_dwordx4,
// base+lane*16) -> 8 S-MFMA -> 32 exp2 -> 16 cvt_pk -> 8 PV-MFMA.
// 1-deep manual pipeline. End: two-phase Red reduction.
// ------------------------------------------------------------------
template<bool DIV>
__global__ __launch_bounds__(256, 2) void fused_kernel(
    const unsigned short* __restrict__ PCK,   // packed CKQ fragments
    const unsigned short* __restrict__ PBX,   // PBT (F1) or QSTP (F2)
    unsigned short* __restrict__ C,           // CB12 [2048][2048]
    float* __restrict__ Lg)                   // [16][2048] (F1 only)
{
  __shared__ __align__(16) float Red[2][64][68];   // ~34.8 KB
  __shared__ float L_lds[64];
  int tid = threadIdx.x, l = tid & 63, w = tid >> 6;
  int zr = l & 31, hi = l >> 5;
  int lin = blockIdx.x;                      // 512 blocks, bijective XCD swizzle
  int wgid = (lin & 7) * 64 + (lin >> 3);
  int h = wgid >> 5, pB = wgid & 31, p0 = pB * 64;
  int cbA = DIV ? h : 16 + h;                // inner cols (F1: K, F2: Q)
  int cbB = DIV ? 16 + h : h;                // persist cols (F1: Q, F2: K)
  const bf16x8* PCKf = (const bf16x8*)PCK;
  const bf16x8* PBXf = (const bf16x8*)PBX;

  // persistent S B-fragments (2 x 32-persist sets)
  bf16x8 bs[2][4];
  #pragma unroll
  for (int ps = 0; ps < 2; ps++)
    #pragma unroll
    for (int kz = 0; kz < 4; kz++)
      bs[ps][kz] = PCKf[((size_t)(cbB * 64 + pB * 2 + ps) * 4 + kz) * 64 + l];

  auto load = [&](bf16x8 (&a_)[4], bf16x8 (&pb_)[2][2], int rb){
    #pragma unroll
    for (int kz = 0; kz < 4; kz++)
      a_[kz] = PCKf[((size_t)(cbA * 64 + rb) * 4 + kz) * 64 + l];
    #pragma unroll
    for (int zb = 0; zb < 2; zb++)
      #pragma unroll
      for (int ks = 0; ks < 2; ks++)
        pb_[zb][ks] = PBXf[((size_t)((h * 2 + zb) * 64 + rb) * 2 + ks) * 64 + l];
  };

  f32x16 acc_pv[2][2] = {};                  // [ps][zb]
  float lsum[2] = {0.f, 0.f};
  bf16x8 a_c[4], pb_c[2][2];
  load(a_c, pb_c, w * 16);

  for (int t = 0; t < 16; t++) {
    bf16x8 a_n[4], pb_n[2][2];
    if (t + 1 < 16) load(a_n, pb_n, w * 16 + t + 1);
    // ---- S: inner-32 x persist-64, contract z=64
    f32x16 acc_s[2] = {};
    #pragma unroll
    for (int kz = 0; kz < 4; kz++) {
      acc_s[0] = __builtin_amdgcn_mfma_f32_32x32x16_bf16(a_c[kz], bs[0][kz], acc_s[0], 0, 0, 0);
      acc_s[1] = __builtin_amdgcn_mfma_f32_32x32x16_bf16(a_c[kz], bs[1][kz], acc_s[1], 0, 0, 0);
    }
    // ---- exp2(SCL*acc); acc halves are the PV A-fragments (verified sigma)
    union { bf16x8 v; uint32_t u[4]; } pu[2][2];
    #pragma unroll
    for (int ps = 0; ps < 2; ps++) {
      float ev[16];
      #pragma unroll
      for (int r = 0; r < 16; r++) ev[r] = exp2f(acc_s[ps][r] * SCL);
      if (DIV) {
        #pragma unroll
        for (int r = 0; r < 16; r++) lsum[ps] += ev[r];
      }
      #pragma unroll
      for (int ks = 0; ks < 2; ks++)
        #pragma unroll
        for (int i = 0; i < 4; i++)
          asm("v_cvt_pk_bf16_f32 %0, %1, %2"
              : "=v"(pu[ps][ks].u[i]) : "v"(ev[8 * ks + 2 * i]), "v"(ev[8 * ks + 2 * i + 1]));
    }
    // ---- PV: persist-64 x z-64, contract this tile's inner-32
    #pragma unroll
    for (int zb = 0; zb < 2; zb++)
      #pragma unroll
      for (int ks = 0; ks < 2; ks++) {
        acc_pv[0][zb] = __builtin_amdgcn_mfma_f32_32x32x16_bf16(pu[0][ks].v, pb_c[zb][ks], acc_pv[0][zb], 0, 0, 0);
        acc_pv[1][zb] = __builtin_amdgcn_mfma_f32_32x32x16_bf16(pu[1][ks].v, pb_c[zb][ks], acc_pv[1][zb], 0, 0, 0);
      }
    #pragma unroll
    for (int kz = 0; kz < 4; kz++) a_c[kz] = a_n[kz];
    #pragma unroll
    for (int zb = 0; zb < 2; zb++)
      #pragma unroll
      for (int ks = 0; ks < 2; ks++) pb_c[zb][ks] = pb_n[zb][ks];
  }

  // ---- cross-wave (4 inner-quarter) two-phase reduction
  if (w >= 2) {
    #pragma unroll
    for (int ps = 0; ps < 2; ps++)
      #pragma unroll
      for (int zb = 0; zb < 2; zb++) {
        int z = zb * 32 + zr;
        #pragma unroll
        for (int u = 0; u < 4; u++) {
          int p = ps * 32 + 8 * u + 4 * hi;
          f32x4 q;
          q[0] = acc_pv[ps][zb][4 * u];     q[1] = acc_pv[ps][zb][4 * u + 1];
          q[2] = acc_pv[ps][zb][4 * u + 2]; q[3] = acc_pv[ps][zb][4 * u + 3];
          *(f32x4*)&Red[w - 2][z][p] = q;
        }
      }
  }
  if (DIV && tid < 64) L_lds[tid] = 0.f;
  __syncthreads();
  if (w < 2) {
    #pragma unroll
    for (int ps = 0; ps < 2; ps++)
      #pragma unroll
      for (int zb = 0; zb < 2; zb++) {
        int z = zb * 32 + zr;
        #pragma unroll
        for (int u = 0; u < 4; u++) {
          int p = ps * 32 + 8 * u + 4 * hi;
          float* slot = &Red[w][z][p];
          f32x4 q = *(f32x4*)slot;
          q[0] += acc_pv[ps][zb][4 * u];     q[1] += acc_pv[ps][zb][4 * u + 1];
          q[2] += acc_pv[ps][zb][4 * u + 2]; q[3] += acc_pv[ps][zb][4 * u + 3];
          *(f32x4*)slot = q;
        }
      }
  }
  if (DIV) {
    #pragma unroll
    for (int ps = 0; ps < 2; ps++) {
      float s = lsum[ps];
      s += __shfl_xor(s, 32);                // combine hi halves (same persist col)
      if (hi == 0) atomicAdd(&L_lds[ps * 32 + zr], s);
    }
  }
  __syncthreads();
  if (DIV && tid < 64) Lg[(size_t)h * NT + p0 + tid] = L_lds[tid];
  // output: thread -> p = tid>>2 (0..63), z-range (tid&3)*16
  int p = tid >> 2, z16 = (tid & 3) * 16;
  float inv = DIV ? 1.0f / L_lds[p] : 1.0f;
  int cbase = DIV ? h * 64 : TD + h * 64;
  unsigned short ob[16];
  #pragma unroll
  for (int i = 0; i < 16; i++) {
    int z = z16 + i;
    float x = Red[0][z][p] + Red[1][z][p];
    ob[i] = f2bf(x * inv);
  }
  unsigned short* dst = C + (size_t)(p0 + p) * 2048 + cbase + z16;
  *(ushort4*)dst        = *(ushort4*)&ob[0];
  *(ushort4*)(dst + 4)  = *(ushort4*)&ob[4];
  *(ushort4*)(dst + 8)  = *(ushort4*)&ob[8];
  *(ushort4*)(dst + 12) = *(ushort4*)&ob[12];
}

// ------------------------------------------------------------------
extern "C" void kernel_launch(void* const* d_in, const int* in_sizes, int n_in,
                              void* d_out, int out_size, void* d_ws, size_t ws_size,
                              hipStream_t stream)
{
  (void)in_sizes; (void)n_in; (void)out_size; (void)ws_size;
  const float* g  = (const float*)d_in[0];
  const float* Wk = (const float*)d_in[1];
  const float* Wq = (const float*)d_in[2];

  char* ws = (char*)d_ws;
  size_t off = 0;
  auto alloc = [&](size_t b) -> char* {
    char* p = ws + off; off += (b + 255) & ~((size_t)255); return p;
  };
  unsigned short* gbf  = (unsigned short*)alloc((size_t)NT * TD * 2);     // 4 MB
  unsigned short* wkq  = (unsigned short*)alloc((size_t)2 * TD * TD * 2); // 4 MB
  unsigned short* twqk = (unsigned short*)alloc((size_t)TD * 2048 * 2);   // 4 MB
  unsigned short* CKQ  = (unsigned short*)alloc((size_t)NT * 2048 * 2);   // 8 MB
  unsigned short* PCK  = (unsigned short*)alloc((size_t)NT * 2048 * 2);   // 8 MB
  unsigned short* PBT  = (unsigned short*)alloc((size_t)TD * NT * 2);     // 4 MB
  unsigned short* QSTP = (unsigned short*)alloc((size_t)TD * NT * 2);     // 4 MB
  unsigned short* CB12 = (unsigned short*)alloc((size_t)NT * 2048 * 2);   // 8 MB
  float*          Lbuf = (float*)alloc((size_t)NH * NT * 4);              // 128 KB

  prep_kernel<<<dim3(4096), dim3(256), 0, stream>>>(g, Wk, Wq, gbf, wkq, twqk);

  // K,Q = g * [Wk;Wq]^T -> CKQ [tok][2048] (row-major)
  btg2_kernel<128, 64, 0, 2><<<dim3(16, 32), dim3(256), 0, stream>>>(
      gbf, TD, wkq, TD, TD, (void*)CKQ);

  // packed operand layouts
  pack_pck<<<dim3(2048), dim3(256), 0, stream>>>(CKQ, PCK);
  pack_pbx<false><<<dim3(2048), dim3(256), 0, stream>>>(CKQ, nullptr, PBT);

  // F1: B1 (normalized) -> CB12 cols [h*64, h*64+64), plus L
  fused_kernel<true><<<dim3(512), dim3(256), 0, stream>>>(PCK, PBT, CB12, Lbuf);

  // QSTP = packed Q^T / L
  pack_pbx<true><<<dim3(2048), dim3(256), 0, stream>>>(CKQ, Lbuf, QSTP);

  // F2: B2 -> CB12 cols [1024+h*64, ...)
  fused_kernel<false><<<dim3(512), dim3(256), 0, stream>>>(PCK, QSTP, CB12, nullptr);

  // out = -( CB12 * twqk^T )   (f32) — 128x64 tile, 256 blocks (1/CU)
  btg2_kernel<128, 64, 4, 2><<<dim3(16, 16), dim3(256), 0, stream>>>(
      CB12, 2048, twqk, 2048, 2048, d_out);
}

// Round 15
// 107.058 us; speedup vs baseline: 1.1430x; 1.0986x over previous
//
#include <hip/hip_runtime.h>
#include <stdint.h>

#define NT 2048     // tokens
#define TD 1024     // token dim
#define NH 16       // heads
static constexpr float SCL = 0.18033688011112042f;  // beta*log2(e), applied in exp2

typedef __attribute__((ext_vector_type(8))) short bf16x8;
typedef __attribute__((ext_vector_type(4))) float f32x4;
typedef __attribute__((ext_vector_type(16))) float f32x16;
typedef __attribute__((address_space(3))) uint32_t lds_u32;
typedef __attribute__((address_space(1))) uint32_t glb_u32;

__device__ __forceinline__ float bf2f(unsigned short u){
  union { uint32_t u32; float f; } v; v.u32 = ((uint32_t)u) << 16; return v.f;
}
__device__ __forceinline__ unsigned short f2bf(float f){
  union { float f; uint32_t u; } v; v.f = f;
  uint32_t r = v.u + 0x7fffu + ((v.u >> 16) & 1u);   // RNE
  return (unsigned short)(r >> 16);
}
// 128B-row tile (8x16B slots), phys slot = kc ^ (row&7)  (btg2 staging)
__device__ __forceinline__ bf16x8 ld8(const unsigned short* base, int row, int kc){
  return *(const bf16x8*)((const char*)base + row*128 + ((kc ^ (row & 7)) << 4));
}
template<int N> __device__ __forceinline__ void wait_vm_lgkm0(){
  if constexpr (N == 0)      asm volatile("s_waitcnt vmcnt(0) lgkmcnt(0)" ::: "memory");
  else if constexpr (N == 4) asm volatile("s_waitcnt vmcnt(4) lgkmcnt(0)" ::: "memory");
  else if constexpr (N == 6) asm volatile("s_waitcnt vmcnt(6) lgkmcnt(0)" ::: "memory");
  __builtin_amdgcn_sched_barrier(0);
}

// ------------------------------------------------------------------
// prep: gbf = bf16(g); wkq = bf16([Wk;Wq]) rows hz2 x 1024;
//       TWP = twqk in out-GEMM B-fragment layout:
//         fragment (db in [0,32), jz in [0,128)): lane l, elem e:
//           d = db*32 + (l&31);  j = jz*16 + 8*(l>>5) + e
//           value = j<1024 ? Wq[j][d] : Wk[j-1024][d]
//         flat bf16x8 idx: (db*128 + jz)*64 + l
// ------------------------------------------------------------------
__global__ __launch_bounds__(256) void prep_kernel(
    const float* __restrict__ g, const float* __restrict__ Wk, const float* __restrict__ Wq,
    unsigned short* __restrict__ gbf, unsigned short* __restrict__ wkq,
    unsigned short* __restrict__ TWP)
{
  int b = blockIdx.x;
  if (b < 1024) {
    int base = b * 2048 + threadIdx.x;
    #pragma unroll
    for (int i = 0; i < 8; i++) { int idx = base + i * 256; gbf[idx] = f2bf(g[idx]); }
  } else if (b < 2048) {
    int base = (b - 1024) * 2048 + threadIdx.x;
    #pragma unroll
    for (int i = 0; i < 8; i++) {
      int idx = base + i * 256;
      float v = (idx < (1 << 20)) ? Wk[idx] : Wq[idx - (1 << 20)];
      wkq[idx] = f2bf(v);
    }
  } else {
    int t = b - 2048;                  // 512 = 32 db x 16 jzg
    int db = t & 31, jzg = t >> 5;
    int d0 = db * 32, j0 = jzg * 128;
    __shared__ unsigned short tile[128][33];   // [j-local][d-local]
    int tid = threadIdx.x;
    const float* src = (j0 < 1024) ? Wq : Wk;
    int jb = (j0 < 1024) ? j0 : (j0 - 1024);
    #pragma unroll
    for (int i = 0; i < 16; i++) {
      int idx = i * 256 + tid, r = idx >> 5, c = idx & 31;
      tile[r][c] = f2bf(src[(size_t)(jb + r) * 1024 + d0 + c]);
    }
    __syncthreads();
    int jq = tid >> 6, l = tid & 63;
    #pragma unroll
    for (int f = 0; f < 2; f++) {
      int jzl = jq * 2 + f;
      unsigned short ob[8];
      #pragma unroll
      for (int e = 0; e < 8; e++)
        ob[e] = tile[jzl * 16 + 8 * (l >> 5) + e][l & 31];
      unsigned short* dst = TWP + ((size_t)(db * 128 + jzg * 8 + jzl) * 64 + l) * 8;
      *(ushort4*)dst       = *(ushort4*)&ob[0];
      *(ushort4*)(dst + 4) = *(ushort4*)&ob[4];
    }
  }
}

// ------------------------------------------------------------------
// pack_pck: PCK fragment layout for S-operands (A and B share the map).
//   fragment (cb in [0,32), rb in [0,64), kz in [0,4)): lane l, elem e:
//     tok = rb*32 + (l&31);  z = kz*16 + 8*(l>>5) + e;  col = cb*64 + z
// ------------------------------------------------------------------
__global__ __launch_bounds__(256) void pack_pck(const unsigned short* __restrict__ CKQ,
                                                unsigned short* __restrict__ PCK)
{
  int tile = blockIdx.x;             // 2048 = 32 cb x 64 rb
  int cb = tile >> 6, rb = tile & 63;
  __shared__ unsigned short t[32][72];   // 32 tok x 64 z (stride 144B, 8B-aligned)
  int tid = threadIdx.x;
  int r = tid >> 3, c0 = (tid & 7) * 8;
  const unsigned short* src = CKQ + (size_t)(rb * 32 + r) * 2048 + cb * 64 + c0;
  *(ushort4*)&t[r][c0]     = *(const ushort4*)src;
  *(ushort4*)&t[r][c0 + 4] = *(const ushort4*)(src + 4);
  __syncthreads();
  int kz = tid >> 6, l = tid & 63;
  int zl = kz * 16 + 8 * (l >> 5);
  ushort4 lo = *(ushort4*)&t[l & 31][zl];
  ushort4 hi4 = *(ushort4*)&t[l & 31][zl + 4];
  unsigned short* dst = PCK + ((size_t)(tile * 4 + kz) * 64 + l) * 8;
  *(ushort4*)dst       = lo;
  *(ushort4*)(dst + 4) = hi4;
}

// ------------------------------------------------------------------
// pack_pbx: PBT (DIVL=false: K^T) / QSTP (DIVL=true: Q^T / L) PV-B fragments.
//   fragment ((h,zb), qb in [0,64), ks in [0,2)): lane l, elem e:
//     z-row = h*64 + zb*32 + (l&31)
//     q     = qb*32 + 16*ks + 8*(e>>2) + 4*(l>>5) + (e&3)     [sigma baked in]
//     value = CKQ[q][colbase + (l&31)]  (/ L[h][q] for QSTP)
// ------------------------------------------------------------------
template<bool DIVL>
__global__ __launch_bounds__(256) void pack_pbx(const unsigned short* __restrict__ CKQ,
                                                const float* __restrict__ L,
                                                unsigned short* __restrict__ PBX)
{
  int bid = blockIdx.x;              // 2048 = (16h x 2zb) x 64 qb
  int qb = bid & 63, hz = bid >> 6;  // hz = h*2+zb
  int h = hz >> 1, zb = hz & 1;
  int colbase = (DIVL ? 1024 : 0) + h * 64 + zb * 32;
  __shared__ unsigned short tq[32][36];   // [q-local][z-local]
  __shared__ float rcpL[32];
  int tid = threadIdx.x;
  int r = tid >> 3, c0 = (tid & 7) * 4;
  *(ushort4*)&tq[r][c0] =
      *(const ushort4*)(CKQ + (size_t)(qb * 32 + r) * 2048 + colbase + c0);
  if (DIVL && tid < 32) rcpL[tid] = 1.0f / L[(size_t)h * NT + qb * 32 + tid];
  __syncthreads();
  if (tid < 128) {
    int ks = tid >> 6, l = tid & 63;
    int zl = l & 31, hi = l >> 5;
    unsigned short ob[8];
    #pragma unroll
    for (int e = 0; e < 8; e++) {
      int ql = 16 * ks + 8 * (e >> 2) + 4 * hi + (e & 3);
      unsigned short v = tq[ql][zl];
      if (DIVL) v = f2bf(bf2f(v) * rcpL[ql]);
      ob[e] = v;
    }
    unsigned short* dst = PBX + ((size_t)(bid * 2 + ks) * 64 + l) * 8;
    *(ushort4*)dst       = *(ushort4*)&ob[0];
    *(ushort4*)(dst + 4) = *(ushort4*)&ob[4];
  }
}

// ------------------------------------------------------------------
// btg2: C = A[M x K] * BT[N x K]^T, bf16, BK=64, triple-buffered counted vmcnt.
// EPI 0: C0 = bf16 C (ld 2048), coalesced rows only                  [KQ]
// ------------------------------------------------------------------
template<int TM, int TN, int EPI, int WPE>
__global__ __launch_bounds__(256, WPE) void btg2_kernel(
    const unsigned short* __restrict__ A, int lda,
    const unsigned short* __restrict__ BT, int ldb,
    int Kdim, void* C0)
{
  constexpr int WM = TM / 2, WN = TN / 2, FM = WM / 16, FN = WN / 16;
  constexpr int AC = TM / 32, BC = TN / 32, LOADS = AC + BC;
  __shared__ __align__(16) unsigned short As[3][TM * 64];
  __shared__ __align__(16) unsigned short Bs[3][TN * 64];
  int tid = threadIdx.x, lane = tid & 63, wave = tid >> 6;
  int wr = wave >> 1, wc = wave & 1, lrow = lane & 15, g = lane >> 4;
  int bm = blockIdx.x * TM, bn = blockIdx.y * TN;

  auto stage = [&](unsigned short* bufA, unsigned short* bufB, int kk) {
    #pragma unroll
    for (int i = 0; i < AC; i++) {
      int c = i * 256 + tid, row = c >> 3, sl = ((c & 7) ^ (row & 7)) << 3;
      __builtin_amdgcn_global_load_lds((glb_u32*)(A + (size_t)(bm + row) * lda + kk + sl),
          (lds_u32*)((char*)bufA + i * 4096 + wave * 1024), 16, 0, 0);
    }
    #pragma unroll
    for (int i = 0; i < BC; i++) {
      int c = i * 256 + tid, row = c >> 3, sl = ((c & 7) ^ (row & 7)) << 3;
      __builtin_amdgcn_global_load_lds((glb_u32*)(BT + (size_t)(bn + row) * ldb + kk + sl),
          (lds_u32*)((char*)bufB + i * 4096 + wave * 1024), 16, 0, 0);
    }
  };

  f32x4 acc[FM][FN] = {};
  int nt = Kdim >> 6;
  stage(As[0], Bs[0], 0);
  stage(As[1], Bs[1], 64);
  wait_vm_lgkm0<LOADS>();          // tile0 landed; tile1 still in flight
  __builtin_amdgcn_s_barrier();
  int bc = 0;
  for (int t = 0; t < nt; t++) {
    int bp = bc + 2; if (bp >= 3) bp -= 3;
    if (t + 2 < nt) stage(As[bp], Bs[bp], (t + 2) * 64);
    const unsigned short* Ac = As[bc];
    const unsigned short* Bc = Bs[bc];
    #pragma unroll
    for (int k2 = 0; k2 < 2; k2++) {
      bf16x8 a_[FM], b_[FN];
      #pragma unroll
      for (int m = 0; m < FM; m++) a_[m] = ld8(Ac, wr * WM + m * 16 + lrow, k2 * 4 + g);
      #pragma unroll
      for (int n = 0; n < FN; n++) b_[n] = ld8(Bc, wc * WN + n * 16 + lrow, k2 * 4 + g);
      #pragma unroll
      for (int m = 0; m < FM; m++)
        #pragma unroll
        for (int n = 0; n < FN; n++)
          acc[m][n] = __builtin_amdgcn_mfma_f32_16x16x32_bf16(a_[m], b_[n], acc[m][n], 0, 0, 0);
    }
    if (t + 2 < nt) wait_vm_lgkm0<LOADS>(); else wait_vm_lgkm0<0>();
    __builtin_amdgcn_s_barrier();
    bc = (bc == 2) ? 0 : bc + 1;
  }
  #pragma unroll
  for (int m = 0; m < FM; m++) {
    int rb = bm + wr * WM + m * 16 + 4 * g;
    #pragma unroll
    for (int n = 0; n < FN; n++) {
      int cc = bn + wc * WN + n * 16 + lrow;
      f32x4 v = acc[m][n];
      unsigned short* Cp = (unsigned short*)C0;
      #pragma unroll
      for (int j = 0; j < 4; j++) Cp[(size_t)(rb + j) * 2048 + cc] = f2bf(v[j]);
    }
  }
}

// ------------------------------------------------------------------
// fused v12 structure (verified): zero-barrier, zero-LDS main loop with
// coalesced packed loads. Epilogue now writes PA = CB12 in the out-GEMM
// A-fragment layout: flat ushort ((jz*64+tb)*64 + (tok&31)+32*hj)*8 + ej,
// j = jz*16 + 8*hj + ej, tb = tok>>5.
// ------------------------------------------------------------------
template<bool DIV>
__global__ __launch_bounds__(256, 2) void fused_kernel(
    const unsigned short* __restrict__ PCK,   // packed CKQ fragments
    const unsigned short* __restrict__ PBX,   // PBT (F1) or QSTP (F2)
    unsigned short* __restrict__ PA,          // packed out-GEMM A operand
    float* __restrict__ Lg)                   // [16][2048] (F1 only)
{
  __shared__ __align__(16) float Red[2][64][68];   // ~34.8 KB
  __shared__ float L_lds[64];
  int tid = threadIdx.x, l = tid & 63, w = tid >> 6;
  int zr = l & 31, hi = l >> 5;
  int lin = blockIdx.x;                      // 512 blocks, bijective XCD swizzle
  int wgid = (lin & 7) * 64 + (lin >> 3);
  int h = wgid >> 5, pB = wgid & 31, p0 = pB * 64;
  int cbA = DIV ? h : 16 + h;                // inner cols (F1: K, F2: Q)
  int cbB = DIV ? 16 + h : h;                // persist cols (F1: Q, F2: K)
  const bf16x8* PCKf = (const bf16x8*)PCK;
  const bf16x8* PBXf = (const bf16x8*)PBX;

  // persistent S B-fragments (2 x 32-persist sets)
  bf16x8 bs[2][4];
  #pragma unroll
  for (int ps = 0; ps < 2; ps++)
    #pragma unroll
    for (int kz = 0; kz < 4; kz++)
      bs[ps][kz] = PCKf[((size_t)(cbB * 64 + pB * 2 + ps) * 4 + kz) * 64 + l];

  auto load = [&](bf16x8 (&a_)[4], bf16x8 (&pb_)[2][2], int rb){
    #pragma unroll
    for (int kz = 0; kz < 4; kz++)
      a_[kz] = PCKf[((size_t)(cbA * 64 + rb) * 4 + kz) * 64 + l];
    #pragma unroll
    for (int zb = 0; zb < 2; zb++)
      #pragma unroll
      for (int ks = 0; ks < 2; ks++)
        pb_[zb][ks] = PBXf[((size_t)((h * 2 + zb) * 64 + rb) * 2 + ks) * 64 + l];
  };

  f32x16 acc_pv[2][2] = {};                  // [ps][zb]
  float lsum[2] = {0.f, 0.f};
  bf16x8 a_c[4], pb_c[2][2];
  load(a_c, pb_c, w * 16);

  for (int t = 0; t < 16; t++) {
    bf16x8 a_n[4], pb_n[2][2];
    if (t + 1 < 16) load(a_n, pb_n, w * 16 + t + 1);
    f32x16 acc_s[2] = {};
    #pragma unroll
    for (int kz = 0; kz < 4; kz++) {
      acc_s[0] = __builtin_amdgcn_mfma_f32_32x32x16_bf16(a_c[kz], bs[0][kz], acc_s[0], 0, 0, 0);
      acc_s[1] = __builtin_amdgcn_mfma_f32_32x32x16_bf16(a_c[kz], bs[1][kz], acc_s[1], 0, 0, 0);
    }
    union { bf16x8 v; uint32_t u[4]; } pu[2][2];
    #pragma unroll
    for (int ps = 0; ps < 2; ps++) {
      float ev[16];
      #pragma unroll
      for (int r = 0; r < 16; r++) ev[r] = exp2f(acc_s[ps][r] * SCL);
      if (DIV) {
        #pragma unroll
        for (int r = 0; r < 16; r++) lsum[ps] += ev[r];
      }
      #pragma unroll
      for (int ks = 0; ks < 2; ks++)
        #pragma unroll
        for (int i = 0; i < 4; i++)
          asm("v_cvt_pk_bf16_f32 %0, %1, %2"
              : "=v"(pu[ps][ks].u[i]) : "v"(ev[8 * ks + 2 * i]), "v"(ev[8 * ks + 2 * i + 1]));
    }
    #pragma unroll
    for (int zb = 0; zb < 2; zb++)
      #pragma unroll
      for (int ks = 0; ks < 2; ks++) {
        acc_pv[0][zb] = __builtin_amdgcn_mfma_f32_32x32x16_bf16(pu[0][ks].v, pb_c[zb][ks], acc_pv[0][zb], 0, 0, 0);
        acc_pv[1][zb] = __builtin_amdgcn_mfma_f32_32x32x16_bf16(pu[1][ks].v, pb_c[zb][ks], acc_pv[1][zb], 0, 0, 0);
      }
    #pragma unroll
    for (int kz = 0; kz < 4; kz++) a_c[kz] = a_n[kz];
    #pragma unroll
    for (int zb = 0; zb < 2; zb++)
      #pragma unroll
      for (int ks = 0; ks < 2; ks++) pb_c[zb][ks] = pb_n[zb][ks];
  }

  // ---- cross-wave (4 inner-quarter) two-phase reduction
  if (w >= 2) {
    #pragma unroll
    for (int ps = 0; ps < 2; ps++)
      #pragma unroll
      for (int zb = 0; zb < 2; zb++) {
        int z = zb * 32 + zr;
        #pragma unroll
        for (int u = 0; u < 4; u++) {
          int p = ps * 32 + 8 * u + 4 * hi;
          f32x4 q;
          q[0] = acc_pv[ps][zb][4 * u];     q[1] = acc_pv[ps][zb][4 * u + 1];
          q[2] = acc_pv[ps][zb][4 * u + 2]; q[3] = acc_pv[ps][zb][4 * u + 3];
          *(f32x4*)&Red[w - 2][z][p] = q;
        }
      }
  }
  if (DIV && tid < 64) L_lds[tid] = 0.f;
  __syncthreads();
  if (w < 2) {
    #pragma unroll
    for (int ps = 0; ps < 2; ps++)
      #pragma unroll
      for (int zb = 0; zb < 2; zb++) {
        int z = zb * 32 + zr;
        #pragma unroll
        for (int u = 0; u < 4; u++) {
          int p = ps * 32 + 8 * u + 4 * hi;
          float* slot = &Red[w][z][p];
          f32x4 q = *(f32x4*)slot;
          q[0] += acc_pv[ps][zb][4 * u];     q[1] += acc_pv[ps][zb][4 * u + 1];
          q[2] += acc_pv[ps][zb][4 * u + 2]; q[3] += acc_pv[ps][zb][4 * u + 3];
          *(f32x4*)slot = q;
        }
      }
  }
  if (DIV) {
    #pragma unroll
    for (int ps = 0; ps < 2; ps++) {
      float s = lsum[ps];
      s += __shfl_xor(s, 32);
      if (hi == 0) atomicAdd(&L_lds[ps * 32 + zr], s);
    }
  }
  __syncthreads();
  if (DIV && tid < 64) Lg[(size_t)h * NT + p0 + tid] = L_lds[tid];
  // ---- packed PA write: thread -> tok = p0 + (tid>>2), j-chunk (tid&3)*16
  int p = tid >> 2, z16 = (tid & 3) * 16;
  float inv = DIV ? 1.0f / L_lds[p] : 1.0f;
  int cbase = DIV ? h * 64 : TD + h * 64;
  int jz = (cbase + z16) >> 4;
  int tok = p0 + p, tb = tok >> 5, tl = tok & 31;
  unsigned short ob[16];
  #pragma unroll
  for (int i = 0; i < 16; i++) {
    int z = z16 + i;
    float x = Red[0][z][p] + Red[1][z][p];
    ob[i] = f2bf(x * inv);
  }
  unsigned short* dst = PA + (((size_t)jz * 64 + tb) * 64) * 8;
  *(ushort4*)(dst + tl * 8)            = *(ushort4*)&ob[0];
  *(ushort4*)(dst + tl * 8 + 4)        = *(ushort4*)&ob[4];
  *(ushort4*)(dst + (32 + tl) * 8)     = *(ushort4*)&ob[8];
  *(ushort4*)(dst + (32 + tl) * 8 + 4) = *(ushort4*)&ob[12];
}

// ------------------------------------------------------------------
// out_kernel: out = -(CB12 * twqk^T) from packed PA (A-frags) and TWP
// (B-frags). 512 blocks = 32 tokb x 16 db2, XCD-swizzled; 4 waves =
// K-quarters (jz = w*32..+32); zero-barrier main loop, coalesced dwordx4
// loads, 1-deep pipeline; v12-style two-phase Red[d][tok] reduction.
// ------------------------------------------------------------------
__global__ __launch_bounds__(256, 2) void out_kernel(
    const unsigned short* __restrict__ PA,
    const unsigned short* __restrict__ TWP,
    float* __restrict__ out)
{
  __shared__ __align__(16) float Red[2][64][68];
  int tid = threadIdx.x, l = tid & 63, w = tid >> 6;
  int zr = l & 31, hi = l >> 5;
  int lin = blockIdx.x;
  int wgid = (lin & 7) * 64 + (lin >> 3);
  int tokb = wgid >> 4, db2 = wgid & 15;
  const bf16x8* PAf = (const bf16x8*)PA;
  const bf16x8* TWf = (const bf16x8*)TWP;

  f32x16 acc[2][2] = {};                      // [th tok-half][dh d-half]
  bf16x8 a_c[2], b_c[2];
  auto loadx = [&](bf16x8 (&a_)[2], bf16x8 (&b_)[2], int jz){
    #pragma unroll
    for (int th = 0; th < 2; th++)
      a_[th] = PAf[((size_t)jz * 64 + tokb * 2 + th) * 64 + l];
    #pragma unroll
    for (int dh = 0; dh < 2; dh++)
      b_[dh] = TWf[((size_t)(db2 * 2 + dh) * 128 + jz) * 64 + l];
  };
  loadx(a_c, b_c, w * 32);
  for (int it = 0; it < 32; it++) {
    bf16x8 a_n[2], b_n[2];
    if (it + 1 < 32) loadx(a_n, b_n, w * 32 + it + 1);
    #pragma unroll
    for (int th = 0; th < 2; th++)
      #pragma unroll
      for (int dh = 0; dh < 2; dh++)
        acc[th][dh] = __builtin_amdgcn_mfma_f32_32x32x16_bf16(a_c[th], b_c[dh], acc[th][dh], 0, 0, 0);
    #pragma unroll
    for (int i = 0; i < 2; i++) { a_c[i] = a_n[i]; b_c[i] = b_n[i]; }
  }
  // two-phase cross-wave (K-quarter) reduction: Red[d-local][tok-local]
  if (w >= 2) {
    #pragma unroll
    for (int th = 0; th < 2; th++)
      #pragma unroll
      for (int dh = 0; dh < 2; dh++) {
        int d = dh * 32 + zr;
        #pragma unroll
        for (int u = 0; u < 4; u++) {
          int tk = th * 32 + 8 * u + 4 * hi;
          f32x4 q;
          q[0] = acc[th][dh][4 * u];     q[1] = acc[th][dh][4 * u + 1];
          q[2] = acc[th][dh][4 * u + 2]; q[3] = acc[th][dh][4 * u + 3];
          *(f32x4*)&Red[w - 2][d][tk] = q;
        }
      }
  }
  __syncthreads();
  if (w < 2) {
    #pragma unroll
    for (int th = 0; th < 2; th++)
      #pragma unroll
      for (int dh = 0; dh < 2; dh++) {
        int d = dh * 32 + zr;
        #pragma unroll
        for (int u = 0; u < 4; u++) {
          int tk = th * 32 + 8 * u + 4 * hi;
          float* slot = &Red[w][d][tk];
          f32x4 q = *(f32x4*)slot;
          q[0] += acc[th][dh][4 * u];     q[1] += acc[th][dh][4 * u + 1];
          q[2] += acc[th][dh][4 * u + 2]; q[3] += acc[th][dh][4 * u + 3];
          *(f32x4*)slot = q;
        }
      }
  }
  __syncthreads();
  // output: thread -> tok local p = tid>>2, d-range (tid&3)*16
  int p = tid >> 2, d16 = (tid & 3) * 16;
  float* dst = out + (size_t)(tokb * 64 + p) * 1024 + db2 * 64 + d16;
  #pragma unroll
  for (int i4 = 0; i4 < 16; i4 += 4) {
    f32x4 r;
    #pragma unroll
    for (int j = 0; j < 4; j++)
      r[j] = -(Red[0][d16 + i4 + j][p] + Red[1][d16 + i4 + j][p]);
    *(f32x4*)(dst + i4) = r;
  }
}

// ------------------------------------------------------------------
extern "C" void kernel_launch(void* const* d_in, const int* in_sizes, int n_in,
                              void* d_out, int out_size, void* d_ws, size_t ws_size,
                              hipStream_t stream)
{
  (void)in_sizes; (void)n_in; (void)out_size; (void)ws_size;
  const float* g  = (const float*)d_in[0];
  const float* Wk = (const float*)d_in[1];
  const float* Wq = (const float*)d_in[2];

  char* ws = (char*)d_ws;
  size_t off = 0;
  auto alloc = [&](size_t b) -> char* {
    char* p = ws + off; off += (b + 255) & ~((size_t)255); return p;
  };
  unsigned short* gbf  = (unsigned short*)alloc((size_t)NT * TD * 2);     // 4 MB
  unsigned short* wkq  = (unsigned short*)alloc((size_t)2 * TD * TD * 2); // 4 MB
  unsigned short* TWP  = (unsigned short*)alloc((size_t)TD * 2048 * 2);   // 4 MB
  unsigned short* CKQ  = (unsigned short*)alloc((size_t)NT * 2048 * 2);   // 8 MB
  unsigned short* PCK  = (unsigned short*)alloc((size_t)NT * 2048 * 2);   // 8 MB
  unsigned short* PBT  = (unsigned short*)alloc((size_t)TD * NT * 2);     // 4 MB
  unsigned short* QSTP = (unsigned short*)alloc((size_t)TD * NT * 2);     // 4 MB
  unsigned short* PA   = (unsigned short*)alloc((size_t)NT * 2048 * 2);   // 8 MB
  float*          Lbuf = (float*)alloc((size_t)NH * NT * 4);              // 128 KB

  prep_kernel<<<dim3(2560), dim3(256), 0, stream>>>(g, Wk, Wq, gbf, wkq, TWP);

  // K,Q = g * [Wk;Wq]^T -> CKQ [tok][2048] (row-major)
  btg2_kernel<128, 64, 0, 2><<<dim3(16, 32), dim3(256), 0, stream>>>(
      gbf, TD, wkq, TD, TD, (void*)CKQ);

  // packed operand layouts
  pack_pck<<<dim3(2048), dim3(256), 0, stream>>>(CKQ, PCK);
  pack_pbx<false><<<dim3(2048), dim3(256), 0, stream>>>(CKQ, nullptr, PBT);

  // F1: B1 (normalized) -> PA fragments jz 0..63, plus L
  fused_kernel<true><<<dim3(512), dim3(256), 0, stream>>>(PCK, PBT, PA, Lbuf);

  // QSTP = packed Q^T / L
  pack_pbx<true><<<dim3(2048), dim3(256), 0, stream>>>(CKQ, Lbuf, QSTP);

  // F2: B2 -> PA fragments jz 64..127
  fused_kernel<false><<<dim3(512), dim3(256), 0, stream>>>(PCK, QSTP, PA, nullptr);

  // out = -(PA . TWP^T) from packed fragments
  out_kernel<<<dim3(512), dim3(256), 0, stream>>>(PA, TWP, (float*)d_out);
}

// Round 16
// 104.578 us; speedup vs baseline: 1.1701x; 1.0237x over previous
//
#include <hip/hip_runtime.h>
#include <stdint.h>

#define NT 2048     // tokens
#define TD 1024     // token dim
#define NH 16       // heads
static constexpr float SCL = 0.18033688011112042f;  // beta*log2(e), applied in exp2

typedef __attribute__((ext_vector_type(8))) short bf16x8;
typedef __attribute__((ext_vector_type(4))) float f32x4;
typedef __attribute__((ext_vector_type(16))) float f32x16;

__device__ __forceinline__ float bf2f(unsigned short u){
  union { uint32_t u32; float f; } v; v.u32 = ((uint32_t)u) << 16; return v.f;
}
__device__ __forceinline__ unsigned short f2bf(float f){
  union { float f; uint32_t u; } v; v.f = f;
  uint32_t r = v.u + 0x7fffu + ((v.u >> 16) & 1u);   // RNE
  return (unsigned short)(r >> 16);
}

// ------------------------------------------------------------------
// prep: packs all three weight/input operands into MFMA-fragment layouts.
//  PG  (g A-frags):   frag (tb2 in[0,64), dz in[0,64)): lane l, elem e:
//                     tok = tb2*32+(l&31), d = dz*16+8*(l>>5)+e
//  PW  (wkq B-frags): frag (cb2 in[0,64), dz): c = cb2*32+(l&31), d same map;
//                     row c<1024 -> Wk[c][d], else Wq[c-1024][d]
//  TWP (out B-frags): frag (db in[0,32), jz in[0,128)): d = db*32+(l&31),
//                     j = jz*16+8*(l>>5)+e; j<1024 -> Wq[j][d] else Wk[j-1024][d]
// ------------------------------------------------------------------
__global__ __launch_bounds__(256) void prep_kernel(
    const float* __restrict__ g, const float* __restrict__ Wk, const float* __restrict__ Wq,
    unsigned short* __restrict__ PG, unsigned short* __restrict__ PW,
    unsigned short* __restrict__ TWP)
{
  int b = blockIdx.x;
  int tid = threadIdx.x;
  if (b < 2048) {
    // PG (b<1024) / PW (b>=1024) tile jobs: 32 rows x 64 d, f32 -> fragments
    bool isW = (b >= 1024);
    int bb = isW ? b - 1024 : b;
    int dg = bb & 15, rb2 = bb >> 4;           // d-group (64), row-block (32)
    __shared__ float tile[32][65];
    const float* src;
    int rbase;
    if (!isW) { src = g; rbase = rb2 * 32; }
    else if (rb2 < 32) { src = Wk; rbase = rb2 * 32; }
    else { src = Wq; rbase = rb2 * 32 - 1024; }
    int r = tid >> 3, c0 = (tid & 7) * 8;
    const float* s = src + (size_t)(rbase + r) * 1024 + dg * 64 + c0;
    *(f32x4*)&tile[r][c0]     = *(const f32x4*)s;
    *(f32x4*)&tile[r][c0 + 4] = *(const f32x4*)(s + 4);
    __syncthreads();
    int dzl = tid >> 6, l = tid & 63;
    int dz = dg * 4 + dzl;
    unsigned short ob[8];
    #pragma unroll
    for (int e = 0; e < 8; e++)
      ob[e] = f2bf(tile[l & 31][dzl * 16 + 8 * (l >> 5) + e]);
    unsigned short* dst = (isW ? PW : PG) + ((size_t)(rb2 * 64 + dz) * 64 + l) * 8;
    *(ushort4*)dst       = *(ushort4*)&ob[0];
    *(ushort4*)(dst + 4) = *(ushort4*)&ob[4];
  } else {
    // TWP jobs (512): verified round-15 branch
    int t = b - 2048;                  // 512 = 32 db x 16 jzg
    int db = t & 31, jzg = t >> 5;
    int d0 = db * 32, j0 = jzg * 128;
    __shared__ unsigned short tile[128][33];   // [j-local][d-local]
    const float* src = (j0 < 1024) ? Wq : Wk;
    int jb = (j0 < 1024) ? j0 : (j0 - 1024);
    #pragma unroll
    for (int i = 0; i < 16; i++) {
      int idx = i * 256 + tid, r = idx >> 5, c = idx & 31;
      tile[r][c] = f2bf(src[(size_t)(jb + r) * 1024 + d0 + c]);
    }
    __syncthreads();
    int jq = tid >> 6, l = tid & 63;
    #pragma unroll
    for (int f = 0; f < 2; f++) {
      int jzl = jq * 2 + f;
      unsigned short ob[8];
      #pragma unroll
      for (int e = 0; e < 8; e++)
        ob[e] = tile[jzl * 16 + 8 * (l >> 5) + e][l & 31];
      unsigned short* dst = TWP + ((size_t)(db * 128 + jzg * 8 + jzl) * 64 + l) * 8;
      *(ushort4*)dst       = *(ushort4*)&ob[0];
      *(ushort4*)(dst + 4) = *(ushort4*)&ob[4];
    }
  }
}

// ------------------------------------------------------------------
// kq_kernel: CKQ = g . wkq^T (contract d=1024) from packed PG/PW.
// 1024 blocks = 32 tokb x 32 cblk (XCD-swizzled); 4 waves = d-quarters;
// per iter {2 a + 2 b coalesced dwordx4 loads, 4 MFMA 32x32x16}; zero
// barriers; two-phase Red reduction; writes CKQ row-major bf16 AND PCK
// fragments (tok = rb*32+(l&31), z = kz*16+8*(l>>5)+e, col = cb*64+z).
// ------------------------------------------------------------------
__global__ __launch_bounds__(256, 2) void kq_kernel(
    const unsigned short* __restrict__ PG,
    const unsigned short* __restrict__ PW,
    unsigned short* __restrict__ CKQ,
    unsigned short* __restrict__ PCK)
{
  __shared__ __align__(16) float Red[2][64][68];
  int tid = threadIdx.x, l = tid & 63, w = tid >> 6;
  int zr = l & 31, hi = l >> 5;
  int lin = blockIdx.x;
  int wgid = (lin & 7) * 128 + (lin >> 3);
  int tokb = wgid >> 5, cblk = wgid & 31;
  const bf16x8* PGf = (const bf16x8*)PG;
  const bf16x8* PWf = (const bf16x8*)PW;

  f32x16 acc[2][2] = {};                      // [th tok-half][ch c-half]
  bf16x8 a_c[2], b_c[2];
  auto loadx = [&](bf16x8 (&a_)[2], bf16x8 (&b_)[2], int dz){
    #pragma unroll
    for (int th = 0; th < 2; th++)
      a_[th] = PGf[((size_t)(tokb * 2 + th) * 64 + dz) * 64 + l];
    #pragma unroll
    for (int ch = 0; ch < 2; ch++)
      b_[ch] = PWf[((size_t)(cblk * 2 + ch) * 64 + dz) * 64 + l];
  };
  loadx(a_c, b_c, w * 16);
  for (int it = 0; it < 16; it++) {
    bf16x8 a_n[2], b_n[2];
    if (it + 1 < 16) loadx(a_n, b_n, w * 16 + it + 1);
    #pragma unroll
    for (int th = 0; th < 2; th++)
      #pragma unroll
      for (int ch = 0; ch < 2; ch++)
        acc[th][ch] = __builtin_amdgcn_mfma_f32_32x32x16_bf16(a_c[th], b_c[ch], acc[th][ch], 0, 0, 0);
    #pragma unroll
    for (int i = 0; i < 2; i++) { a_c[i] = a_n[i]; b_c[i] = b_n[i]; }
  }
  // two-phase cross-wave (d-quarter) reduction: Red[c-local][tok-local]
  if (w >= 2) {
    #pragma unroll
    for (int th = 0; th < 2; th++)
      #pragma unroll
      for (int ch = 0; ch < 2; ch++) {
        int c = ch * 32 + zr;
        #pragma unroll
        for (int u = 0; u < 4; u++) {
          int tk = th * 32 + 8 * u + 4 * hi;
          f32x4 q;
          q[0] = acc[th][ch][4 * u];     q[1] = acc[th][ch][4 * u + 1];
          q[2] = acc[th][ch][4 * u + 2]; q[3] = acc[th][ch][4 * u + 3];
          *(f32x4*)&Red[w - 2][c][tk] = q;
        }
      }
  }
  __syncthreads();
  if (w < 2) {
    #pragma unroll
    for (int th = 0; th < 2; th++)
      #pragma unroll
      for (int ch = 0; ch < 2; ch++) {
        int c = ch * 32 + zr;
        #pragma unroll
        for (int u = 0; u < 4; u++) {
          int tk = th * 32 + 8 * u + 4 * hi;
          float* slot = &Red[w][c][tk];
          f32x4 q = *(f32x4*)slot;
          q[0] += acc[th][ch][4 * u];     q[1] += acc[th][ch][4 * u + 1];
          q[2] += acc[th][ch][4 * u + 2]; q[3] += acc[th][ch][4 * u + 3];
          *(f32x4*)slot = q;
        }
      }
  }
  __syncthreads();
  // output: thread -> tok local p = tid>>2, c-range (tid&3)*16
  int p = tid >> 2, c16 = (tid & 3) * 16;
  int tok = tokb * 64 + p;
  unsigned short ob[16];
  #pragma unroll
  for (int i = 0; i < 16; i++)
    ob[i] = f2bf(Red[0][c16 + i][p] + Red[1][c16 + i][p]);
  // CKQ row-major (consumed by pack_pbx)
  unsigned short* dst = CKQ + (size_t)tok * 2048 + cblk * 64 + c16;
  *(ushort4*)dst        = *(ushort4*)&ob[0];
  *(ushort4*)(dst + 4)  = *(ushort4*)&ob[4];
  *(ushort4*)(dst + 8)  = *(ushort4*)&ob[8];
  *(ushort4*)(dst + 12) = *(ushort4*)&ob[12];
  // PCK fragments (consumed by fused): cb = cblk, kz = tid&3
  int rb = tok >> 5, tl = tok & 31, kz = tid & 3;
  unsigned short* dstp = PCK + (((size_t)(cblk * 64 + rb) * 4 + kz) * 64) * 8;
  *(ushort4*)(dstp + tl * 8)            = *(ushort4*)&ob[0];
  *(ushort4*)(dstp + tl * 8 + 4)        = *(ushort4*)&ob[4];
  *(ushort4*)(dstp + (32 + tl) * 8)     = *(ushort4*)&ob[8];
  *(ushort4*)(dstp + (32 + tl) * 8 + 4) = *(ushort4*)&ob[12];
}

// ------------------------------------------------------------------
// pack_pbx: PBT (DIVL=false: K^T) / QSTP (DIVL=true: Q^T / L) PV-B fragments.
//   fragment ((h,zb), qb in [0,64), ks in [0,2)): lane l, elem e:
//     z-row = h*64 + zb*32 + (l&31)
//     q     = qb*32 + 16*ks + 8*(e>>2) + 4*(l>>5) + (e&3)     [sigma baked in]
//     value = CKQ[q][colbase + (l&31)]  (/ L[h][q] for QSTP)
// ------------------------------------------------------------------
template<bool DIVL>
__global__ __launch_bounds__(256) void pack_pbx(const unsigned short* __restrict__ CKQ,
                                                const float* __restrict__ L,
                                                unsigned short* __restrict__ PBX)
{
  int bid = blockIdx.x;              // 2048 = (16h x 2zb) x 64 qb
  int qb = bid & 63, hz = bid >> 6;  // hz = h*2+zb
  int h = hz >> 1, zb = hz & 1;
  int colbase = (DIVL ? 1024 : 0) + h * 64 + zb * 32;
  __shared__ unsigned short tq[32][36];   // [q-local][z-local]
  __shared__ float rcpL[32];
  int tid = threadIdx.x;
  int r = tid >> 3, c0 = (tid & 7) * 4;
  *(ushort4*)&tq[r][c0] =
      *(const ushort4*)(CKQ + (size_t)(qb * 32 + r) * 2048 + colbase + c0);
  if (DIVL && tid < 32) rcpL[tid] = 1.0f / L[(size_t)h * NT + qb * 32 + tid];
  __syncthreads();
  if (tid < 128) {
    int ks = tid >> 6, l = tid & 63;
    int zl = l & 31, hi = l >> 5;
    unsigned short ob[8];
    #pragma unroll
    for (int e = 0; e < 8; e++) {
      int ql = 16 * ks + 8 * (e >> 2) + 4 * hi + (e & 3);
      unsigned short v = tq[ql][zl];
      if (DIVL) v = f2bf(bf2f(v) * rcpL[ql]);
      ob[e] = v;
    }
    unsigned short* dst = PBX + ((size_t)(bid * 2 + ks) * 64 + l) * 8;
    *(ushort4*)dst       = *(ushort4*)&ob[0];
    *(ushort4*)(dst + 4) = *(ushort4*)&ob[4];
  }
}

// ------------------------------------------------------------------
// fused (v12/v15 verified): zero-barrier, zero-LDS main loop with coalesced
// packed loads; epilogue writes PA = out-GEMM A-fragments.
// ------------------------------------------------------------------
template<bool DIV>
__global__ __launch_bounds__(256, 2) void fused_kernel(
    const unsigned short* __restrict__ PCK,   // packed CKQ fragments
    const unsigned short* __restrict__ PBX,   // PBT (F1) or QSTP (F2)
    unsigned short* __restrict__ PA,          // packed out-GEMM A operand
    float* __restrict__ Lg)                   // [16][2048] (F1 only)
{
  __shared__ __align__(16) float Red[2][64][68];   // ~34.8 KB
  __shared__ float L_lds[64];
  int tid = threadIdx.x, l = tid & 63, w = tid >> 6;
  int zr = l & 31, hi = l >> 5;
  int lin = blockIdx.x;                      // 512 blocks, bijective XCD swizzle
  int wgid = (lin & 7) * 64 + (lin >> 3);
  int h = wgid >> 5, pB = wgid & 31, p0 = pB * 64;
  int cbA = DIV ? h : 16 + h;                // inner cols (F1: K, F2: Q)
  int cbB = DIV ? 16 + h : h;                // persist cols (F1: Q, F2: K)
  const bf16x8* PCKf = (const bf16x8*)PCK;
  const bf16x8* PBXf = (const bf16x8*)PBX;

  // persistent S B-fragments (2 x 32-persist sets)
  bf16x8 bs[2][4];
  #pragma unroll
  for (int ps = 0; ps < 2; ps++)
    #pragma unroll
    for (int kz = 0; kz < 4; kz++)
      bs[ps][kz] = PCKf[((size_t)(cbB * 64 + pB * 2 + ps) * 4 + kz) * 64 + l];

  auto load = [&](bf16x8 (&a_)[4], bf16x8 (&pb_)[2][2], int rb){
    #pragma unroll
    for (int kz = 0; kz < 4; kz++)
      a_[kz] = PCKf[((size_t)(cbA * 64 + rb) * 4 + kz) * 64 + l];
    #pragma unroll
    for (int zb = 0; zb < 2; zb++)
      #pragma unroll
      for (int ks = 0; ks < 2; ks++)
        pb_[zb][ks] = PBXf[((size_t)((h * 2 + zb) * 64 + rb) * 2 + ks) * 64 + l];
  };

  f32x16 acc_pv[2][2] = {};                  // [ps][zb]
  float lsum[2] = {0.f, 0.f};
  bf16x8 a_c[4], pb_c[2][2];
  load(a_c, pb_c, w * 16);

  for (int t = 0; t < 16; t++) {
    bf16x8 a_n[4], pb_n[2][2];
    if (t + 1 < 16) load(a_n, pb_n, w * 16 + t + 1);
    f32x16 acc_s[2] = {};
    #pragma unroll
    for (int kz = 0; kz < 4; kz++) {
      acc_s[0] = __builtin_amdgcn_mfma_f32_32x32x16_bf16(a_c[kz], bs[0][kz], acc_s[0], 0, 0, 0);
      acc_s[1] = __builtin_amdgcn_mfma_f32_32x32x16_bf16(a_c[kz], bs[1][kz], acc_s[1], 0, 0, 0);
    }
    union { bf16x8 v; uint32_t u[4]; } pu[2][2];
    #pragma unroll
    for (int ps = 0; ps < 2; ps++) {
      float ev[16];
      #pragma unroll
      for (int r = 0; r < 16; r++) ev[r] = exp2f(acc_s[ps][r] * SCL);
      if (DIV) {
        #pragma unroll
        for (int r = 0; r < 16; r++) lsum[ps] += ev[r];
      }
      #pragma unroll
      for (int ks = 0; ks < 2; ks++)
        #pragma unroll
        for (int i = 0; i < 4; i++)
          asm("v_cvt_pk_bf16_f32 %0, %1, %2"
              : "=v"(pu[ps][ks].u[i]) : "v"(ev[8 * ks + 2 * i]), "v"(ev[8 * ks + 2 * i + 1]));
    }
    #pragma unroll
    for (int zb = 0; zb < 2; zb++)
      #pragma unroll
      for (int ks = 0; ks < 2; ks++) {
        acc_pv[0][zb] = __builtin_amdgcn_mfma_f32_32x32x16_bf16(pu[0][ks].v, pb_c[zb][ks], acc_pv[0][zb], 0, 0, 0);
        acc_pv[1][zb] = __builtin_amdgcn_mfma_f32_32x32x16_bf16(pu[1][ks].v, pb_c[zb][ks], acc_pv[1][zb], 0, 0, 0);
      }
    #pragma unroll
    for (int kz = 0; kz < 4; kz++) a_c[kz] = a_n[kz];
    #pragma unroll
    for (int zb = 0; zb < 2; zb++)
      #pragma unroll
      for (int ks = 0; ks < 2; ks++) pb_c[zb][ks] = pb_n[zb][ks];
  }

  // ---- cross-wave (4 inner-quarter) two-phase reduction
  if (w >= 2) {
    #pragma unroll
    for (int ps = 0; ps < 2; ps++)
      #pragma unroll
      for (int zb = 0; zb < 2; zb++) {
        int z = zb * 32 + zr;
        #pragma unroll
        for (int u = 0; u < 4; u++) {
          int p = ps * 32 + 8 * u + 4 * hi;
          f32x4 q;
          q[0] = acc_pv[ps][zb][4 * u];     q[1] = acc_pv[ps][zb][4 * u + 1];
          q[2] = acc_pv[ps][zb][4 * u + 2]; q[3] = acc_pv[ps][zb][4 * u + 3];
          *(f32x4*)&Red[w - 2][z][p] = q;
        }
      }
  }
  if (DIV && tid < 64) L_lds[tid] = 0.f;
  __syncthreads();
  if (w < 2) {
    #pragma unroll
    for (int ps = 0; ps < 2; ps++)
      #pragma unroll
      for (int zb = 0; zb < 2; zb++) {
        int z = zb * 32 + zr;
        #pragma unroll
        for (int u = 0; u < 4; u++) {
          int p = ps * 32 + 8 * u + 4 * hi;
          float* slot = &Red[w][z][p];
          f32x4 q = *(f32x4*)slot;
          q[0] += acc_pv[ps][zb][4 * u];     q[1] += acc_pv[ps][zb][4 * u + 1];
          q[2] += acc_pv[ps][zb][4 * u + 2]; q[3] += acc_pv[ps][zb][4 * u + 3];
          *(f32x4*)slot = q;
        }
      }
  }
  if (DIV) {
    #pragma unroll
    for (int ps = 0; ps < 2; ps++) {
      float s = lsum[ps];
      s += __shfl_xor(s, 32);
      if (hi == 0) atomicAdd(&L_lds[ps * 32 + zr], s);
    }
  }
  __syncthreads();
  if (DIV && tid < 64) Lg[(size_t)h * NT + p0 + tid] = L_lds[tid];
  // ---- packed PA write: thread -> tok = p0 + (tid>>2), j-chunk (tid&3)*16
  int p = tid >> 2, z16 = (tid & 3) * 16;
  float inv = DIV ? 1.0f / L_lds[p] : 1.0f;
  int cbase = DIV ? h * 64 : TD + h * 64;
  int jz = (cbase + z16) >> 4;
  int tok = p0 + p, tb = tok >> 5, tl = tok & 31;
  unsigned short ob[16];
  #pragma unroll
  for (int i = 0; i < 16; i++) {
    int z = z16 + i;
    float x = Red[0][z][p] + Red[1][z][p];
    ob[i] = f2bf(x * inv);
  }
  unsigned short* dst = PA + (((size_t)jz * 64 + tb) * 64) * 8;
  *(ushort4*)(dst + tl * 8)            = *(ushort4*)&ob[0];
  *(ushort4*)(dst + tl * 8 + 4)        = *(ushort4*)&ob[4];
  *(ushort4*)(dst + (32 + tl) * 8)     = *(ushort4*)&ob[8];
  *(ushort4*)(dst + (32 + tl) * 8 + 4) = *(ushort4*)&ob[12];
}

// ------------------------------------------------------------------
// out_kernel (v15 verified): out = -(PA . TWP^T) from packed fragments.
// ------------------------------------------------------------------
__global__ __launch_bounds__(256, 2) void out_kernel(
    const unsigned short* __restrict__ PA,
    const unsigned short* __restrict__ TWP,
    float* __restrict__ out)
{
  __shared__ __align__(16) float Red[2][64][68];
  int tid = threadIdx.x, l = tid & 63, w = tid >> 6;
  int zr = l & 31, hi = l >> 5;
  int lin = blockIdx.x;
  int wgid = (lin & 7) * 64 + (lin >> 3);
  int tokb = wgid >> 4, db2 = wgid & 15;
  const bf16x8* PAf = (const bf16x8*)PA;
  const bf16x8* TWf = (const bf16x8*)TWP;

  f32x16 acc[2][2] = {};                      // [th tok-half][dh d-half]
  bf16x8 a_c[2], b_c[2];
  auto loadx = [&](bf16x8 (&a_)[2], bf16x8 (&b_)[2], int jz){
    #pragma unroll
    for (int th = 0; th < 2; th++)
      a_[th] = PAf[((size_t)jz * 64 + tokb * 2 + th) * 64 + l];
    #pragma unroll
    for (int dh = 0; dh < 2; dh++)
      b_[dh] = TWf[((size_t)(db2 * 2 + dh) * 128 + jz) * 64 + l];
  };
  loadx(a_c, b_c, w * 32);
  for (int it = 0; it < 32; it++) {
    bf16x8 a_n[2], b_n[2];
    if (it + 1 < 32) loadx(a_n, b_n, w * 32 + it + 1);
    #pragma unroll
    for (int th = 0; th < 2; th++)
      #pragma unroll
      for (int dh = 0; dh < 2; dh++)
        acc[th][dh] = __builtin_amdgcn_mfma_f32_32x32x16_bf16(a_c[th], b_c[dh], acc[th][dh], 0, 0, 0);
    #pragma unroll
    for (int i = 0; i < 2; i++) { a_c[i] = a_n[i]; b_c[i] = b_n[i]; }
  }
  if (w >= 2) {
    #pragma unroll
    for (int th = 0; th < 2; th++)
      #pragma unroll
      for (int dh = 0; dh < 2; dh++) {
        int d = dh * 32 + zr;
        #pragma unroll
        for (int u = 0; u < 4; u++) {
          int tk = th * 32 + 8 * u + 4 * hi;
          f32x4 q;
          q[0] = acc[th][dh][4 * u];     q[1] = acc[th][dh][4 * u + 1];
          q[2] = acc[th][dh][4 * u + 2]; q[3] = acc[th][dh][4 * u + 3];
          *(f32x4*)&Red[w - 2][d][tk] = q;
        }
      }
  }
  __syncthreads();
  if (w < 2) {
    #pragma unroll
    for (int th = 0; th < 2; th++)
      #pragma unroll
      for (int dh = 0; dh < 2; dh++) {
        int d = dh * 32 + zr;
        #pragma unroll
        for (int u = 0; u < 4; u++) {
          int tk = th * 32 + 8 * u + 4 * hi;
          float* slot = &Red[w][d][tk];
          f32x4 q = *(f32x4*)slot;
          q[0] += acc[th][dh][4 * u];     q[1] += acc[th][dh][4 * u + 1];
          q[2] += acc[th][dh][4 * u + 2]; q[3] += acc[th][dh][4 * u + 3];
          *(f32x4*)slot = q;
        }
      }
  }
  __syncthreads();
  int p = tid >> 2, d16 = (tid & 3) * 16;
  float* dst = out + (size_t)(tokb * 64 + p) * 1024 + db2 * 64 + d16;
  #pragma unroll
  for (int i4 = 0; i4 < 16; i4 += 4) {
    f32x4 r;
    #pragma unroll
    for (int j = 0; j < 4; j++)
      r[j] = -(Red[0][d16 + i4 + j][p] + Red[1][d16 + i4 + j][p]);
    *(f32x4*)(dst + i4) = r;
  }
}

// ------------------------------------------------------------------
extern "C" void kernel_launch(void* const* d_in, const int* in_sizes, int n_in,
                              void* d_out, int out_size, void* d_ws, size_t ws_size,
                              hipStream_t stream)
{
  (void)in_sizes; (void)n_in; (void)out_size; (void)ws_size;
  const float* g  = (const float*)d_in[0];
  const float* Wk = (const float*)d_in[1];
  const float* Wq = (const float*)d_in[2];

  char* ws = (char*)d_ws;
  size_t off = 0;
  auto alloc = [&](size_t b) -> char* {
    char* p = ws + off; off += (b + 255) & ~((size_t)255); return p;
  };
  unsigned short* PG   = (unsigned short*)alloc((size_t)NT * TD * 2);     // 4 MB
  unsigned short* PW   = (unsigned short*)alloc((size_t)2048 * TD * 2);   // 4 MB
  unsigned short* TWP  = (unsigned short*)alloc((size_t)TD * 2048 * 2);   // 4 MB
  unsigned short* CKQ  = (unsigned short*)alloc((size_t)NT * 2048 * 2);   // 8 MB
  unsigned short* PCK  = (unsigned short*)alloc((size_t)NT * 2048 * 2);   // 8 MB
  unsigned short* PBT  = (unsigned short*)alloc((size_t)TD * NT * 2);     // 4 MB
  unsigned short* QSTP = (unsigned short*)alloc((size_t)TD * NT * 2);     // 4 MB
  unsigned short* PA   = (unsigned short*)alloc((size_t)NT * 2048 * 2);   // 8 MB
  float*          Lbuf = (float*)alloc((size_t)NH * NT * 4);              // 128 KB

  // pack g -> PG, [Wk;Wq] -> PW, twqk -> TWP
  prep_kernel<<<dim3(2560), dim3(256), 0, stream>>>(g, Wk, Wq, PG, PW, TWP);

  // CKQ = g . wkq^T (row-major + PCK fragments), zero-barrier packed GEMM
  kq_kernel<<<dim3(1024), dim3(256), 0, stream>>>(PG, PW, CKQ, PCK);

  // PBT = packed K^T fragments
  pack_pbx<false><<<dim3(2048), dim3(256), 0, stream>>>(CKQ, nullptr, PBT);

  // F1: B1 (normalized) -> PA fragments jz 0..63, plus L
  fused_kernel<true><<<dim3(512), dim3(256), 0, stream>>>(PCK, PBT, PA, Lbuf);

  // QSTP = packed Q^T / L
  pack_pbx<true><<<dim3(2048), dim3(256), 0, stream>>>(CKQ, Lbuf, QSTP);

  // F2: B2 -> PA fragments jz 64..127
  fused_kernel<false><<<dim3(512), dim3(256), 0, stream>>>(PCK, QSTP, PA, nullptr);

  // out = -(PA . TWP^T) from packed fragments
  out_kernel<<<dim3(512), dim3(256), 0, stream>>>(PA, TWP, (float*)d_out);
}

// Round 17
// 99.007 us; speedup vs baseline: 1.2360x; 1.0563x over previous
//
#include <hip/hip_runtime.h>
#include <stdint.h>

#define NT 2048     // tokens
#define TD 1024     // token dim
#define NH 16       // heads
static constexpr float SCL = 0.18033688011112042f;  // beta*log2(e), applied in exp2

typedef __attribute__((ext_vector_type(8))) short bf16x8;
typedef __attribute__((ext_vector_type(4))) float f32x4;
typedef __attribute__((ext_vector_type(16))) float f32x16;

__device__ __forceinline__ float bf2f(unsigned short u){
  union { uint32_t u32; float f; } v; v.u32 = ((uint32_t)u) << 16; return v.f;
}
__device__ __forceinline__ unsigned short f2bf(float f){
  union { float f; uint32_t u; } v; v.f = f;
  uint32_t r = v.u + 0x7fffu + ((v.u >> 16) & 1u);   // RNE
  return (unsigned short)(r >> 16);
}

// ------------------------------------------------------------------
// prep (round-16 verified): packs g -> PG (A-frags), [Wk;Wq] -> PW (B-frags),
// twqk -> TWP (out-GEMM B-frags).
// ------------------------------------------------------------------
__global__ __launch_bounds__(256) void prep_kernel(
    const float* __restrict__ g, const float* __restrict__ Wk, const float* __restrict__ Wq,
    unsigned short* __restrict__ PG, unsigned short* __restrict__ PW,
    unsigned short* __restrict__ TWP)
{
  int b = blockIdx.x;
  int tid = threadIdx.x;
  if (b < 2048) {
    bool isW = (b >= 1024);
    int bb = isW ? b - 1024 : b;
    int dg = bb & 15, rb2 = bb >> 4;
    __shared__ float tile[32][65];
    const float* src;
    int rbase;
    if (!isW) { src = g; rbase = rb2 * 32; }
    else if (rb2 < 32) { src = Wk; rbase = rb2 * 32; }
    else { src = Wq; rbase = rb2 * 32 - 1024; }
    int r = tid >> 3, c0 = (tid & 7) * 8;
    const float* s = src + (size_t)(rbase + r) * 1024 + dg * 64 + c0;
    *(f32x4*)&tile[r][c0]     = *(const f32x4*)s;
    *(f32x4*)&tile[r][c0 + 4] = *(const f32x4*)(s + 4);
    __syncthreads();
    int dzl = tid >> 6, l = tid & 63;
    int dz = dg * 4 + dzl;
    unsigned short ob[8];
    #pragma unroll
    for (int e = 0; e < 8; e++)
      ob[e] = f2bf(tile[l & 31][dzl * 16 + 8 * (l >> 5) + e]);
    unsigned short* dst = (isW ? PW : PG) + ((size_t)(rb2 * 64 + dz) * 64 + l) * 8;
    *(ushort4*)dst       = *(ushort4*)&ob[0];
    *(ushort4*)(dst + 4) = *(ushort4*)&ob[4];
  } else {
    int t = b - 2048;                  // 512 = 32 db x 16 jzg
    int db = t & 31, jzg = t >> 5;
    int d0 = db * 32, j0 = jzg * 128;
    __shared__ unsigned short tile[128][33];
    const float* src = (j0 < 1024) ? Wq : Wk;
    int jb = (j0 < 1024) ? j0 : (j0 - 1024);
    #pragma unroll
    for (int i = 0; i < 16; i++) {
      int idx = i * 256 + tid, r = idx >> 5, c = idx & 31;
      tile[r][c] = f2bf(src[(size_t)(jb + r) * 1024 + d0 + c]);
    }
    __syncthreads();
    int jq = tid >> 6, l = tid & 63;
    #pragma unroll
    for (int f = 0; f < 2; f++) {
      int jzl = jq * 2 + f;
      unsigned short ob[8];
      #pragma unroll
      for (int e = 0; e < 8; e++)
        ob[e] = tile[jzl * 16 + 8 * (l >> 5) + e][l & 31];
      unsigned short* dst = TWP + ((size_t)(db * 128 + jzg * 8 + jzl) * 64 + l) * 8;
      *(ushort4*)dst       = *(ushort4*)&ob[0];
      *(ushort4*)(dst + 4) = *(ushort4*)&ob[4];
    }
  }
}

// ------------------------------------------------------------------
// kq_kernel (round-16 verified core): CKQ-values = g . wkq^T from packed
// PG/PW; zero-barrier; two-phase Red reduction. Epilogue writes PCK frags
// AND (cblk<16) PBT fragments DIRECTLY (pack_pbx<false> folded in; values
// f2bf(Red0+Red1) = bit-identical to old CKQ->pack path). CKQ buffer gone.
// ------------------------------------------------------------------
__global__ __launch_bounds__(256, 2) void kq_kernel(
    const unsigned short* __restrict__ PG,
    const unsigned short* __restrict__ PW,
    unsigned short* __restrict__ PCK,
    unsigned short* __restrict__ PBT)
{
  __shared__ __align__(16) float Red[2][64][68];
  int tid = threadIdx.x, l = tid & 63, w = tid >> 6;
  int zr = l & 31, hi = l >> 5;
  int lin = blockIdx.x;
  int wgid = (lin & 7) * 128 + (lin >> 3);
  int tokb = wgid >> 5, cblk = wgid & 31;
  const bf16x8* PGf = (const bf16x8*)PG;
  const bf16x8* PWf = (const bf16x8*)PW;

  f32x16 acc[2][2] = {};                      // [th tok-half][ch c-half]
  bf16x8 a_c[2], b_c[2];
  auto loadx = [&](bf16x8 (&a_)[2], bf16x8 (&b_)[2], int dz){
    #pragma unroll
    for (int th = 0; th < 2; th++)
      a_[th] = PGf[((size_t)(tokb * 2 + th) * 64 + dz) * 64 + l];
    #pragma unroll
    for (int ch = 0; ch < 2; ch++)
      b_[ch] = PWf[((size_t)(cblk * 2 + ch) * 64 + dz) * 64 + l];
  };
  loadx(a_c, b_c, w * 16);
  for (int it = 0; it < 16; it++) {
    bf16x8 a_n[2], b_n[2];
    if (it + 1 < 16) loadx(a_n, b_n, w * 16 + it + 1);
    #pragma unroll
    for (int th = 0; th < 2; th++)
      #pragma unroll
      for (int ch = 0; ch < 2; ch++)
        acc[th][ch] = __builtin_amdgcn_mfma_f32_32x32x16_bf16(a_c[th], b_c[ch], acc[th][ch], 0, 0, 0);
    #pragma unroll
    for (int i = 0; i < 2; i++) { a_c[i] = a_n[i]; b_c[i] = b_n[i]; }
  }
  if (w >= 2) {
    #pragma unroll
    for (int th = 0; th < 2; th++)
      #pragma unroll
      for (int ch = 0; ch < 2; ch++) {
        int c = ch * 32 + zr;
        #pragma unroll
        for (int u = 0; u < 4; u++) {
          int tk = th * 32 + 8 * u + 4 * hi;
          f32x4 q;
          q[0] = acc[th][ch][4 * u];     q[1] = acc[th][ch][4 * u + 1];
          q[2] = acc[th][ch][4 * u + 2]; q[3] = acc[th][ch][4 * u + 3];
          *(f32x4*)&Red[w - 2][c][tk] = q;
        }
      }
  }
  __syncthreads();
  if (w < 2) {
    #pragma unroll
    for (int th = 0; th < 2; th++)
      #pragma unroll
      for (int ch = 0; ch < 2; ch++) {
        int c = ch * 32 + zr;
        #pragma unroll
        for (int u = 0; u < 4; u++) {
          int tk = th * 32 + 8 * u + 4 * hi;
          float* slot = &Red[w][c][tk];
          f32x4 q = *(f32x4*)slot;
          q[0] += acc[th][ch][4 * u];     q[1] += acc[th][ch][4 * u + 1];
          q[2] += acc[th][ch][4 * u + 2]; q[3] += acc[th][ch][4 * u + 3];
          *(f32x4*)slot = q;
        }
      }
  }
  __syncthreads();
  // PCK fragments: thread -> tok local p = tid>>2, c-range (tid&3)*16
  int p = tid >> 2, c16 = (tid & 3) * 16;
  int tok = tokb * 64 + p;
  unsigned short ob[16];
  #pragma unroll
  for (int i = 0; i < 16; i++)
    ob[i] = f2bf(Red[0][c16 + i][p] + Red[1][c16 + i][p]);
  int rb = tok >> 5, tl = tok & 31, kz = tid & 3;
  unsigned short* dstp = PCK + (((size_t)(cblk * 64 + rb) * 4 + kz) * 64) * 8;
  *(ushort4*)(dstp + tl * 8)            = *(ushort4*)&ob[0];
  *(ushort4*)(dstp + tl * 8 + 4)        = *(ushort4*)&ob[4];
  *(ushort4*)(dstp + (32 + tl) * 8)     = *(ushort4*)&ob[8];
  *(ushort4*)(dstp + (32 + tl) * 8 + 4) = *(ushort4*)&ob[12];
  // PBT fragments (K columns only): pack_pbx<false> folded in
  if (cblk < 16) {
    int h = cblk;
    int zb = (tid >> 7) & 1, qh = (tid >> 6) & 1;
    int cl = zb * 32 + zr;
    #pragma unroll
    for (int ks = 0; ks < 2; ks++) {
      unsigned short o2[8];
      #pragma unroll
      for (int e = 0; e < 8; e++) {
        int ql = 32 * qh + 16 * ks + 8 * (e >> 2) + 4 * hi + (e & 3);
        o2[e] = f2bf(Red[0][cl][ql] + Red[1][cl][ql]);
      }
      unsigned short* dq = PBT +
          ((((size_t)(h * 2 + zb) * 64 + tokb * 2 + qh) * 2 + ks) * 64 + l) * 8;
      *(ushort4*)dq       = *(ushort4*)&o2[0];
      *(ushort4*)(dq + 4) = *(ushort4*)&o2[4];
    }
  }
}

// ------------------------------------------------------------------
// fused (v12/v15/v16 verified core): zero-barrier packed-load kernel.
// F1 (DIV=true) epilogue additionally emits QSTP fragments directly from
// its bs registers (Q bf16, same bits as old CKQ path) / L, via an 8.7 KB
// LDS tile — pack_pbx<true> folded in.
// ------------------------------------------------------------------
template<bool DIV>
__global__ __launch_bounds__(256, 2) void fused_kernel(
    const unsigned short* __restrict__ PCK,   // packed CKQ fragments
    const unsigned short* __restrict__ PBX,   // PBT (F1) or QSTP (F2)
    unsigned short* __restrict__ PA,          // packed out-GEMM A operand
    unsigned short* __restrict__ QSTP)        // F1 only: packed Q^T/L frags
{
  __shared__ __align__(16) float Red[2][64][68];   // ~34.8 KB
  __shared__ float L_lds[64];
  __shared__ unsigned short Qt[64][68];            // 8.7 KB (F1 only)
  int tid = threadIdx.x, l = tid & 63, w = tid >> 6;
  int zr = l & 31, hi = l >> 5;
  int lin = blockIdx.x;                      // 512 blocks, bijective XCD swizzle
  int wgid = (lin & 7) * 64 + (lin >> 3);
  int h = wgid >> 5, pB = wgid & 31, p0 = pB * 64;
  int cbA = DIV ? h : 16 + h;                // inner cols (F1: K, F2: Q)
  int cbB = DIV ? 16 + h : h;                // persist cols (F1: Q, F2: K)
  const bf16x8* PCKf = (const bf16x8*)PCK;
  const bf16x8* PBXf = (const bf16x8*)PBX;

  // persistent S B-fragments (2 x 32-persist sets)
  bf16x8 bs[2][4];
  #pragma unroll
  for (int ps = 0; ps < 2; ps++)
    #pragma unroll
    for (int kz = 0; kz < 4; kz++)
      bs[ps][kz] = PCKf[((size_t)(cbB * 64 + pB * 2 + ps) * 4 + kz) * 64 + l];

  auto load = [&](bf16x8 (&a_)[4], bf16x8 (&pb_)[2][2], int rb){
    #pragma unroll
    for (int kz = 0; kz < 4; kz++)
      a_[kz] = PCKf[((size_t)(cbA * 64 + rb) * 4 + kz) * 64 + l];
    #pragma unroll
    for (int zb = 0; zb < 2; zb++)
      #pragma unroll
      for (int ks = 0; ks < 2; ks++)
        pb_[zb][ks] = PBXf[((size_t)((h * 2 + zb) * 64 + rb) * 2 + ks) * 64 + l];
  };

  f32x16 acc_pv[2][2] = {};                  // [ps][zb]
  float lsum[2] = {0.f, 0.f};
  bf16x8 a_c[4], pb_c[2][2];
  load(a_c, pb_c, w * 16);

  for (int t = 0; t < 16; t++) {
    bf16x8 a_n[4], pb_n[2][2];
    if (t + 1 < 16) load(a_n, pb_n, w * 16 + t + 1);
    f32x16 acc_s[2] = {};
    #pragma unroll
    for (int kz = 0; kz < 4; kz++) {
      acc_s[0] = __builtin_amdgcn_mfma_f32_32x32x16_bf16(a_c[kz], bs[0][kz], acc_s[0], 0, 0, 0);
      acc_s[1] = __builtin_amdgcn_mfma_f32_32x32x16_bf16(a_c[kz], bs[1][kz], acc_s[1], 0, 0, 0);
    }
    union { bf16x8 v; uint32_t u[4]; } pu[2][2];
    #pragma unroll
    for (int ps = 0; ps < 2; ps++) {
      float ev[16];
      #pragma unroll
      for (int r = 0; r < 16; r++) ev[r] = exp2f(acc_s[ps][r] * SCL);
      if (DIV) {
        #pragma unroll
        for (int r = 0; r < 16; r++) lsum[ps] += ev[r];
      }
      #pragma unroll
      for (int ks = 0; ks < 2; ks++)
        #pragma unroll
        for (int i = 0; i < 4; i++)
          asm("v_cvt_pk_bf16_f32 %0, %1, %2"
              : "=v"(pu[ps][ks].u[i]) : "v"(ev[8 * ks + 2 * i]), "v"(ev[8 * ks + 2 * i + 1]));
    }
    #pragma unroll
    for (int zb = 0; zb < 2; zb++)
      #pragma unroll
      for (int ks = 0; ks < 2; ks++) {
        acc_pv[0][zb] = __builtin_amdgcn_mfma_f32_32x32x16_bf16(pu[0][ks].v, pb_c[zb][ks], acc_pv[0][zb], 0, 0, 0);
        acc_pv[1][zb] = __builtin_amdgcn_mfma_f32_32x32x16_bf16(pu[1][ks].v, pb_c[zb][ks], acc_pv[1][zb], 0, 0, 0);
      }
    #pragma unroll
    for (int kz = 0; kz < 4; kz++) a_c[kz] = a_n[kz];
    #pragma unroll
    for (int zb = 0; zb < 2; zb++)
      #pragma unroll
      for (int ks = 0; ks < 2; ks++) pb_c[zb][ks] = pb_n[zb][ks];
  }

  // ---- cross-wave (4 inner-quarter) two-phase reduction
  if (w >= 2) {
    #pragma unroll
    for (int ps = 0; ps < 2; ps++)
      #pragma unroll
      for (int zb = 0; zb < 2; zb++) {
        int z = zb * 32 + zr;
        #pragma unroll
        for (int u = 0; u < 4; u++) {
          int p = ps * 32 + 8 * u + 4 * hi;
          f32x4 q;
          q[0] = acc_pv[ps][zb][4 * u];     q[1] = acc_pv[ps][zb][4 * u + 1];
          q[2] = acc_pv[ps][zb][4 * u + 2]; q[3] = acc_pv[ps][zb][4 * u + 3];
          *(f32x4*)&Red[w - 2][z][p] = q;
        }
      }
  }
  if (DIV && tid < 64) L_lds[tid] = 0.f;
  __syncthreads();
  if (w < 2) {
    #pragma unroll
    for (int ps = 0; ps < 2; ps++)
      #pragma unroll
      for (int zb = 0; zb < 2; zb++) {
        int z = zb * 32 + zr;
        #pragma unroll
        for (int u = 0; u < 4; u++) {
          int p = ps * 32 + 8 * u + 4 * hi;
          float* slot = &Red[w][z][p];
          f32x4 q = *(f32x4*)slot;
          q[0] += acc_pv[ps][zb][4 * u];     q[1] += acc_pv[ps][zb][4 * u + 1];
          q[2] += acc_pv[ps][zb][4 * u + 2]; q[3] += acc_pv[ps][zb][4 * u + 3];
          *(f32x4*)slot = q;
        }
      }
  }
  if (DIV) {
    #pragma unroll
    for (int ps = 0; ps < 2; ps++) {
      float s = lsum[ps];
      s += __shfl_xor(s, 32);
      if (hi == 0) atomicAdd(&L_lds[ps * 32 + zr], s);
    }
  }
  __syncthreads();
  // ---- packed PA write: thread -> tok = p0 + (tid>>2), j-chunk (tid&3)*16
  int p = tid >> 2, z16 = (tid & 3) * 16;
  float inv = DIV ? 1.0f / L_lds[p] : 1.0f;
  int cbase = DIV ? h * 64 : TD + h * 64;
  int jz = (cbase + z16) >> 4;
  int tok = p0 + p, tb = tok >> 5, tl = tok & 31;
  unsigned short ob[16];
  #pragma unroll
  for (int i = 0; i < 16; i++) {
    int z = z16 + i;
    float x = Red[0][z][p] + Red[1][z][p];
    ob[i] = f2bf(x * inv);
  }
  unsigned short* dst = PA + (((size_t)jz * 64 + tb) * 64) * 8;
  *(ushort4*)(dst + tl * 8)            = *(ushort4*)&ob[0];
  *(ushort4*)(dst + tl * 8 + 4)        = *(ushort4*)&ob[4];
  *(ushort4*)(dst + (32 + tl) * 8)     = *(ushort4*)&ob[8];
  *(ushort4*)(dst + (32 + tl) * 8 + 4) = *(ushort4*)&ob[12];

  // ---- F1 only: emit QSTP fragments (pack_pbx<true> folded in)
  if (DIV) {
    // dump Q/L tile Qt[q-local][z] from bs registers
    #pragma unroll
    for (int ps = 0; ps < 2; ps++) {
      float iq = 1.0f / L_lds[ps * 32 + zr];
      #pragma unroll
      for (int kz = 0; kz < 4; kz++) {
        unsigned short t8[8];
        #pragma unroll
        for (int e = 0; e < 8; e++)
          t8[e] = f2bf(bf2f((unsigned short)bs[ps][kz][e]) * iq);
        unsigned short* qd = &Qt[ps * 32 + zr][kz * 16 + 8 * hi];
        *(ushort4*)qd       = *(ushort4*)&t8[0];
        *(ushort4*)(qd + 4) = *(ushort4*)&t8[4];
      }
    }
    __syncthreads();
    int zb = (tid >> 7) & 1, qh = (tid >> 6) & 1;
    #pragma unroll
    for (int ks = 0; ks < 2; ks++) {
      unsigned short o2[8];
      #pragma unroll
      for (int e = 0; e < 8; e++) {
        int ql = 32 * qh + 16 * ks + 8 * (e >> 2) + 4 * hi + (e & 3);
        o2[e] = Qt[ql][zb * 32 + zr];
      }
      unsigned short* dq = QSTP +
          ((((size_t)(h * 2 + zb) * 64 + pB * 2 + qh) * 2 + ks) * 64 + l) * 8;
      *(ushort4*)dq       = *(ushort4*)&o2[0];
      *(ushort4*)(dq + 4) = *(ushort4*)&o2[4];
    }
  }
}

// ------------------------------------------------------------------
// out_kernel (v15 verified): out = -(PA . TWP^T) from packed fragments.
// ------------------------------------------------------------------
__global__ __launch_bounds__(256, 2) void out_kernel(
    const unsigned short* __restrict__ PA,
    const unsigned short* __restrict__ TWP,
    float* __restrict__ out)
{
  __shared__ __align__(16) float Red[2][64][68];
  int tid = threadIdx.x, l = tid & 63, w = tid >> 6;
  int zr = l & 31, hi = l >> 5;
  int lin = blockIdx.x;
  int wgid = (lin & 7) * 64 + (lin >> 3);
  int tokb = wgid >> 4, db2 = wgid & 15;
  const bf16x8* PAf = (const bf16x8*)PA;
  const bf16x8* TWf = (const bf16x8*)TWP;

  f32x16 acc[2][2] = {};                      // [th tok-half][dh d-half]
  bf16x8 a_c[2], b_c[2];
  auto loadx = [&](bf16x8 (&a_)[2], bf16x8 (&b_)[2], int jz){
    #pragma unroll
    for (int th = 0; th < 2; th++)
      a_[th] = PAf[((size_t)jz * 64 + tokb * 2 + th) * 64 + l];
    #pragma unroll
    for (int dh = 0; dh < 2; dh++)
      b_[dh] = TWf[((size_t)(db2 * 2 + dh) * 128 + jz) * 64 + l];
  };
  loadx(a_c, b_c, w * 32);
  for (int it = 0; it < 32; it++) {
    bf16x8 a_n[2], b_n[2];
    if (it + 1 < 32) loadx(a_n, b_n, w * 32 + it + 1);
    #pragma unroll
    for (int th = 0; th < 2; th++)
      #pragma unroll
      for (int dh = 0; dh < 2; dh++)
        acc[th][dh] = __builtin_amdgcn_mfma_f32_32x32x16_bf16(a_c[th], b_c[dh], acc[th][dh], 0, 0, 0);
    #pragma unroll
    for (int i = 0; i < 2; i++) { a_c[i] = a_n[i]; b_c[i] = b_n[i]; }
  }
  if (w >= 2) {
    #pragma unroll
    for (int th = 0; th < 2; th++)
      #pragma unroll
      for (int dh = 0; dh < 2; dh++) {
        int d = dh * 32 + zr;
        #pragma unroll
        for (int u = 0; u < 4; u++) {
          int tk = th * 32 + 8 * u + 4 * hi;
          f32x4 q;
          q[0] = acc[th][dh][4 * u];     q[1] = acc[th][dh][4 * u + 1];
          q[2] = acc[th][dh][4 * u + 2]; q[3] = acc[th][dh][4 * u + 3];
          *(f32x4*)&Red[w - 2][d][tk] = q;
        }
      }
  }
  __syncthreads();
  if (w < 2) {
    #pragma unroll
    for (int th = 0; th < 2; th++)
      #pragma unroll
      for (int dh = 0; dh < 2; dh++) {
        int d = dh * 32 + zr;
        #pragma unroll
        for (int u = 0; u < 4; u++) {
          int tk = th * 32 + 8 * u + 4 * hi;
          float* slot = &Red[w][d][tk];
          f32x4 q = *(f32x4*)slot;
          q[0] += acc[th][dh][4 * u];     q[1] += acc[th][dh][4 * u + 1];
          q[2] += acc[th][dh][4 * u + 2]; q[3] += acc[th][dh][4 * u + 3];
          *(f32x4*)slot = q;
        }
      }
  }
  __syncthreads();
  int p = tid >> 2, d16 = (tid & 3) * 16;
  float* dst = out + (size_t)(tokb * 64 + p) * 1024 + db2 * 64 + d16;
  #pragma unroll
  for (int i4 = 0; i4 < 16; i4 += 4) {
    f32x4 r;
    #pragma unroll
    for (int j = 0; j < 4; j++)
      r[j] = -(Red[0][d16 + i4 + j][p] + Red[1][d16 + i4 + j][p]);
    *(f32x4*)(dst + i4) = r;
  }
}

// ------------------------------------------------------------------
extern "C" void kernel_launch(void* const* d_in, const int* in_sizes, int n_in,
                              void* d_out, int out_size, void* d_ws, size_t ws_size,
                              hipStream_t stream)
{
  (void)in_sizes; (void)n_in; (void)out_size; (void)ws_size;
  const float* g  = (const float*)d_in[0];
  const float* Wk = (const float*)d_in[1];
  const float* Wq = (const float*)d_in[2];

  char* ws = (char*)d_ws;
  size_t off = 0;
  auto alloc = [&](size_t b) -> char* {
    char* p = ws + off; off += (b + 255) & ~((size_t)255); return p;
  };
  unsigned short* PG   = (unsigned short*)alloc((size_t)NT * TD * 2);     // 4 MB
  unsigned short* PW   = (unsigned short*)alloc((size_t)2048 * TD * 2);   // 4 MB
  unsigned short* TWP  = (unsigned short*)alloc((size_t)TD * 2048 * 2);   // 4 MB
  unsigned short* PCK  = (unsigned short*)alloc((size_t)NT * 2048 * 2);   // 8 MB
  unsigned short* PBT  = (unsigned short*)alloc((size_t)TD * NT * 2);     // 4 MB
  unsigned short* QSTP = (unsigned short*)alloc((size_t)TD * NT * 2);     // 4 MB
  unsigned short* PA   = (unsigned short*)alloc((size_t)NT * 2048 * 2);   // 8 MB

  // pack g -> PG, [Wk;Wq] -> PW, twqk -> TWP
  prep_kernel<<<dim3(2560), dim3(256), 0, stream>>>(g, Wk, Wq, PG, PW, TWP);

  // KQ GEMM -> PCK fragments + PBT fragments (pack folded into epilogue)
  kq_kernel<<<dim3(1024), dim3(256), 0, stream>>>(PG, PW, PCK, PBT);

  // F1: B1 -> PA fragments jz 0..63; QSTP fragments (pack folded in)
  fused_kernel<true><<<dim3(512), dim3(256), 0, stream>>>(PCK, PBT, PA, QSTP);

  // F2: B2 -> PA fragments jz 64..127
  fused_kernel<false><<<dim3(512), dim3(256), 0, stream>>>(PCK, QSTP, PA, nullptr);

  // out = -(PA . TWP^T) from packed fragments
  out_kernel<<<dim3(512), dim3(256), 0, stream>>>(PA, TWP, (float*)d_out);
}